// Round 1
// baseline (303.334 us; speedup 1.0000x reference)
//
#include <hip/hip_runtime.h>

// VQSpeaker: obs[32,2048,128] -> 3-layer MLP -> x[65536,64] -> VQ argmin over
// codebook[2048,64] -> (msg = codebook[idx], idx, cmt_loss).
//
// Round 9: vq = R3's structure with 32 points/wave (2 A-frag groups) to halve
//          codebook L2 re-read traffic (2 GB -> 1 GB). Candidate screening /
//          exact-rescore machinery semantically identical per point.
//          mlp unchanged (MFMA fp16 3-product split).
//
// d_out layout (float32): msg[4194304] | idx[65536] (as float) | loss[1]
// d_ws: e2[2048] | cbh bf16 256KB | cbl bf16 256KB | w1h/w1l 16KB ea |
//       w2h/w2l/w3h/w3l 8KB ea   (total ~584 KB)

#define NPTS    65536
#define IN_DIM  128
#define HID     64
#define OUT_DIM 64
#define CB_N    2048
#define MSG_ELEMS (NPTS * OUT_DIM)
#define LOSS_SCALE (1.0f / 4194304.0f)
#define MARG 0.5f          // R3-proven screening margin
#define CAND_CAP 1024      // scaled 2x with points/block (was 512 for 64 pts)
#define VQ_PTS 128         // points per block (4 waves x 32)

typedef __attribute__((ext_vector_type(8))) short short8;
typedef _Float16 half8 __attribute__((ext_vector_type(8)));
typedef __attribute__((ext_vector_type(4))) float f32x4;

__device__ __forceinline__ unsigned short f2bf(float f) {
    unsigned u = __float_as_uint(f);
    u += 0x7FFF + ((u >> 16) & 1);          // RN-even to bf16
    return (unsigned short)(u >> 16);
}
__device__ __forceinline__ float bf2f(unsigned short h) {
    return __uint_as_float((unsigned)h << 16);
}

__global__ void zero_loss_kernel(float* __restrict__ loss) { *loss = 0.0f; }

__global__ __launch_bounds__(256) void e2_kernel(
    const float* __restrict__ codebook, float* __restrict__ e2)
{
    const int c = blockIdx.x * 256 + threadIdx.x;
    const float4* row = (const float4*)(codebook + (long)c * OUT_DIM);
    float s = 0.0f;
    #pragma unroll
    for (int m = 0; m < 16; ++m) {
        const float4 v = row[m];
        s += v.x * v.x + v.y * v.y + v.z * v.z + v.w * v.w;
    }
    e2[c] = s;
}

// Permute codebook into MFMA B-fragment order, split hi/lo bf16 (R3-verified).
__global__ __launch_bounds__(256) void prep_cb(
    const float* __restrict__ cb,
    unsigned short* __restrict__ cbh, unsigned short* __restrict__ cbl)
{
    const int id = blockIdx.x * 256 + threadIdx.x;  // 0..4095: (code n, half h)
    const int n = id >> 1, h = id & 1;
    const int t = n >> 4, l15 = n & 15;
    const float* src = cb + (long)n * OUT_DIM + h * 32;
    #pragma unroll
    for (int quad = 0; quad < 4; ++quad) {
        short8 hi, lo;
        #pragma unroll
        for (int j = 0; j < 8; ++j) {
            const float f = src[quad * 8 + j];
            const unsigned short hb = f2bf(f);
            hi[j] = (short)hb;
            lo[j] = (short)f2bf(f - bf2f(hb));
        }
        const long dst = ((long)(t * 2 + h) * 64 + quad * 16 + l15) * 8;
        *(short8*)(cbh + dst) = hi;
        *(short8*)(cbl + dst) = lo;
    }
}

// Permute W1/W2/W3 into MFMA B-frag order, fp16 hi/lo split.
// frag[lane][j] = W[kc*32 + (lane>>4)*8 + j][nt*16 + (lane&15)], frag = kc*4+nt
__global__ __launch_bounds__(256) void prep_w(
    const float* __restrict__ W1, const float* __restrict__ W2,
    const float* __restrict__ W3,
    _Float16* __restrict__ w1h, _Float16* __restrict__ w1l,
    _Float16* __restrict__ w2h, _Float16* __restrict__ w2l,
    _Float16* __restrict__ w3h, _Float16* __restrict__ w3l)
{
    const int id = blockIdx.x * 256 + threadIdx.x;   // 0..2047
    const int lane = id & 63;
    const int m = lane & 15, quad = lane >> 4;
    const float* W; _Float16 *dh, *dl; int frag;
    if (id < 1024)      { W = W1; dh = w1h; dl = w1l; frag = id >> 6; }          // 16 frags
    else if (id < 1536) { W = W2; dh = w2h; dl = w2l; frag = (id - 1024) >> 6; } // 8
    else                { W = W3; dh = w3h; dl = w3l; frag = (id - 1536) >> 6; } // 8
    const int kc = frag >> 2, nt = frag & 3;
    half8 hi, lo;
    #pragma unroll
    for (int j = 0; j < 8; ++j) {
        const float v = W[(long)(kc * 32 + quad * 8 + j) * 64 + nt * 16 + m];
        hi[j] = (_Float16)v;
        lo[j] = (_Float16)(v - (float)hi[j]);
    }
    const long dst = (long)(frag * 64 + lane) * 8;
    *(half8*)(dh + dst) = hi;
    *(half8*)(dl + dst) = lo;
}

#define MFMA16(A, B, C) __builtin_amdgcn_mfma_f32_16x16x32_f16(A, B, C, 0, 0, 0)
#define MFMABF(A, B, C) __builtin_amdgcn_mfma_f32_16x16x32_bf16(A, B, C, 0, 0, 0)

__device__ __forceinline__ void split16(const float* xs, half8& h, half8& l) {
    #pragma unroll
    for (int j = 0; j < 8; ++j) {
        h[j] = (_Float16)xs[j];
        l[j] = (_Float16)(xs[j] - (float)h[j]);
    }
}

// ---------------- MLP via MFMA: 64 pts/block, 256 thr = 4 waves -------------
// Wave w owns points w*16..w*16+15 end-to-end; LDS traffic is wave-local so
// no barriers until the final cross-wave coalesced store.
__global__ __launch_bounds__(256) void mlp_mfma(
    const float* __restrict__ obs,
    const float* __restrict__ b1, const float* __restrict__ b2,
    const float* __restrict__ b3,
    const _Float16* __restrict__ w1h, const _Float16* __restrict__ w1l,
    const _Float16* __restrict__ w2h, const _Float16* __restrict__ w2l,
    const _Float16* __restrict__ w3h, const _Float16* __restrict__ w3l,
    float* __restrict__ xout)
{
    __shared__ float hbuf[64 * 68];     // stride 68: <=2-way banks (free)
    const int t = threadIdx.x, lane = t & 63, w = t >> 6;
    const int m = lane & 15, quad = lane >> 4;
    const long base = (long)blockIdx.x * 64;
    const int row0 = w * 16 + quad * 4;         // C-layout write rows (+r)
    const int arow_l = w * 16 + m;              // A-layout read row

    float bb1[4], bb2[4], bb3[4];
    #pragma unroll
    for (int nt = 0; nt < 4; ++nt) {
        bb1[nt] = b1[nt * 16 + m];
        bb2[nt] = b2[nt * 16 + m];
        bb3[nt] = b3[nt * 16 + m];
    }

    // ---- A-frags from obs (fp16 split), K = 128 -> 4 chunks ----
    const float* arow = obs + (base + w * 16 + m) * IN_DIM;
    half8 a1h[4], a1l[4];
    #pragma unroll
    for (int kc = 0; kc < 4; ++kc) {
        const float4 va = *(const float4*)(arow + kc * 32 + quad * 8);
        const float4 vb = *(const float4*)(arow + kc * 32 + quad * 8 + 4);
        const float xs[8] = {va.x, va.y, va.z, va.w, vb.x, vb.y, vb.z, vb.w};
        split16(xs, a1h[kc], a1l[kc]);
    }

    // ---- layer 1: [64x128]x[128x64] + b1, relu ----
    #pragma unroll
    for (int nt = 0; nt < 4; ++nt) {
        f32x4 acc = {0.0f, 0.0f, 0.0f, 0.0f};
        #pragma unroll
        for (int kc = 0; kc < 4; ++kc) {
            const long fo = (long)((kc * 4 + nt) * 64 + lane) * 8;
            const half8 wh = *(const half8*)(w1h + fo);
            const half8 wl = *(const half8*)(w1l + fo);
            acc = MFMA16(a1h[kc], wh, acc);
            acc = MFMA16(a1l[kc], wh, acc);
            acc = MFMA16(a1h[kc], wl, acc);
        }
        #pragma unroll
        for (int r = 0; r < 4; ++r) {
            const float v = acc[r] + bb1[nt];
            hbuf[(row0 + r) * 68 + nt * 16 + m] = v > 0.0f ? v : 0.0f;
        }
    }

    // ---- layer 2: [64x64]x[64x64] + b2, relu (A re-split from LDS) ----
    half8 a2h[2], a2l[2];
    #pragma unroll
    for (int kc = 0; kc < 2; ++kc) {
        const float4 va = *(const float4*)&hbuf[arow_l * 68 + kc * 32 + quad * 8];
        const float4 vb = *(const float4*)&hbuf[arow_l * 68 + kc * 32 + quad * 8 + 4];
        const float xs[8] = {va.x, va.y, va.z, va.w, vb.x, vb.y, vb.z, vb.w};
        split16(xs, a2h[kc], a2l[kc]);
    }
    #pragma unroll
    for (int nt = 0; nt < 4; ++nt) {
        f32x4 acc = {0.0f, 0.0f, 0.0f, 0.0f};
        #pragma unroll
        for (int kc = 0; kc < 2; ++kc) {
            const long fo = (long)((kc * 4 + nt) * 64 + lane) * 8;
            const half8 wh = *(const half8*)(w2h + fo);
            const half8 wl = *(const half8*)(w2l + fo);
            acc = MFMA16(a2h[kc], wh, acc);
            acc = MFMA16(a2l[kc], wh, acc);
            acc = MFMA16(a2h[kc], wl, acc);
        }
        #pragma unroll
        for (int r = 0; r < 4; ++r) {
            const float v = acc[r] + bb2[nt];
            hbuf[(row0 + r) * 68 + nt * 16 + m] = v > 0.0f ? v : 0.0f;
        }
    }

    // ---- layer 3: [64x64]x[64x64] + b3 (no relu) ----
    half8 a3h[2], a3l[2];
    #pragma unroll
    for (int kc = 0; kc < 2; ++kc) {
        const float4 va = *(const float4*)&hbuf[arow_l * 68 + kc * 32 + quad * 8];
        const float4 vb = *(const float4*)&hbuf[arow_l * 68 + kc * 32 + quad * 8 + 4];
        const float xs[8] = {va.x, va.y, va.z, va.w, vb.x, vb.y, vb.z, vb.w};
        split16(xs, a3h[kc], a3l[kc]);
    }
    #pragma unroll
    for (int nt = 0; nt < 4; ++nt) {
        f32x4 acc = {0.0f, 0.0f, 0.0f, 0.0f};
        #pragma unroll
        for (int kc = 0; kc < 2; ++kc) {
            const long fo = (long)((kc * 4 + nt) * 64 + lane) * 8;
            const half8 wh = *(const half8*)(w3h + fo);
            const half8 wl = *(const half8*)(w3l + fo);
            acc = MFMA16(a3h[kc], wh, acc);
            acc = MFMA16(a3l[kc], wh, acc);
            acc = MFMA16(a3h[kc], wl, acc);
        }
        #pragma unroll
        for (int r = 0; r < 4; ++r)
            hbuf[(row0 + r) * 68 + nt * 16 + m] = acc[r] + bb3[nt];
    }
    __syncthreads();    // only cross-wave touch: coalesced store below

    float4* og = (float4*)(xout + base * OUT_DIM);
    #pragma unroll
    for (int mm = 0; mm < 4; ++mm) {
        const int v = t + 256 * mm;
        const int p = v >> 4, k4 = v & 15;
        og[v] = *(const float4*)&hbuf[p * 68 + k4 * 4];
    }
}

// exact fp32 distance update (R2/R3 proven numerics)
__device__ __forceinline__ void exact_upd(
    const float* __restrict__ xr, const float* __restrict__ cb,
    const float* __restrict__ e2, int n, float& bd, int& bi)
{
    const float4* xp = (const float4*)xr;
    const float4* cp = (const float4*)(cb + (long)n * OUT_DIM);
    float a0 = 0.0f, a1 = 0.0f;
    #pragma unroll
    for (int m = 0; m < 16; ++m) {
        const float4 xv = xp[m], cv = cp[m];
        a0 = fmaf(xv.x, cv.x, a0); a1 = fmaf(xv.y, cv.y, a1);
        a0 = fmaf(xv.z, cv.z, a0); a1 = fmaf(xv.w, cv.w, a1);
    }
    const float ex = fmaf(-2.0f, a0 + a1, e2[n]);
    if (ex < bd || (ex == bd && n < bi)) { bd = ex; bi = n; }
}

// ---------------- VQ via MFMA: 32 points/wave (2 A-groups), 128 pts/block ---
// Same screening/rescore semantics as R3 per point; B-frag loads amortized
// over 2x more points -> codebook L2 traffic halved (2 GB -> 1 GB).
__global__ __launch_bounds__(256) void vq_mfma(
    const float* __restrict__ cb,
    const unsigned short* __restrict__ cbhp,
    const unsigned short* __restrict__ cblp,
    const float* __restrict__ e2,
    float* __restrict__ msg,        // in: x, out: quantize
    float* __restrict__ idx_out,
    float* __restrict__ loss_out)
{
    __shared__ float best_d_s[4][32][16];   // [wave][pt-in-wave][col]
    __shared__ int   best_i_s[4][32][16];
    __shared__ int   cand_pc[CAND_CAP];     // (p_local<<16) | code
    __shared__ float cand_d[CAND_CAP];
    __shared__ int   cand_cnt;
    __shared__ int   idx_sh[VQ_PTS];
    __shared__ float wred[4];

    const int t = threadIdx.x, lane = t & 63, w = t >> 6;
    const int m = lane & 15, quad = lane >> 4;
    const long base = (long)blockIdx.x * VQ_PTS;

    if (t == 0) cand_cnt = 0;

    // A-frags: 2 groups of 16 points. x[point][k], halves k0=0/32. Built once.
    short8 a0h[2], a0l[2], a1h[2], a1l[2];
    #pragma unroll
    for (int g = 0; g < 2; ++g) {
        const float* xrow = msg + (base + w * 32 + g * 16 + m) * OUT_DIM;
        const float4 xa = *(const float4*)(xrow + quad * 8);
        const float4 xb = *(const float4*)(xrow + quad * 8 + 4);
        const float4 xc = *(const float4*)(xrow + 32 + quad * 8);
        const float4 xd = *(const float4*)(xrow + 32 + quad * 8 + 4);
        const float x0[8] = {xa.x, xa.y, xa.z, xa.w, xb.x, xb.y, xb.z, xb.w};
        const float x1[8] = {xc.x, xc.y, xc.z, xc.w, xd.x, xd.y, xd.z, xd.w};
        #pragma unroll
        for (int j = 0; j < 8; ++j) {
            unsigned short hb = f2bf(x0[j]);
            a0h[g][j] = (short)hb; a0l[g][j] = (short)f2bf(x0[j] - bf2f(hb));
            hb = f2bf(x1[j]);
            a1h[g][j] = (short)hb; a1l[g][j] = (short)f2bf(x1[j] - bf2f(hb));
        }
    }
    __syncthreads();   // cand_cnt visible

    float bd[2][4] = {{3.4e38f, 3.4e38f, 3.4e38f, 3.4e38f},
                      {3.4e38f, 3.4e38f, 3.4e38f, 3.4e38f}};
    int   bi[2][4] = {{0, 0, 0, 0}, {0, 0, 0, 0}};

    // register double-buffered B-frags
    long toff = (long)lane * 8;
    short8 bh0 = *(const short8*)(cbhp + toff);
    short8 bh1 = *(const short8*)(cbhp + toff + 512);
    short8 bl0 = *(const short8*)(cblp + toff);
    short8 bl1 = *(const short8*)(cblp + toff + 512);

    for (int tile = 0; tile < 128; ++tile) {
        const int nt = (tile + 1 < 128) ? tile + 1 : 127;
        const long noff = (long)nt * 1024 + (long)lane * 8;
        const short8 nh0 = *(const short8*)(cbhp + noff);
        const short8 nh1 = *(const short8*)(cbhp + noff + 512);
        const short8 nl0 = *(const short8*)(cblp + noff);
        const short8 nl1 = *(const short8*)(cblp + noff + 512);
        const float e2v = e2[tile * 16 + m];

        // 4 independent 3-deep MFMA chains: [group][k-half]
        f32x4 accA[2] = {{0.0f, 0.0f, 0.0f, 0.0f}, {0.0f, 0.0f, 0.0f, 0.0f}};
        f32x4 accB[2] = {{0.0f, 0.0f, 0.0f, 0.0f}, {0.0f, 0.0f, 0.0f, 0.0f}};
        accA[0] = MFMABF(a0h[0], bh0, accA[0]);
        accA[1] = MFMABF(a0h[1], bh0, accA[1]);
        accB[0] = MFMABF(a1h[0], bh1, accB[0]);
        accB[1] = MFMABF(a1h[1], bh1, accB[1]);
        accA[0] = MFMABF(a0l[0], bh0, accA[0]);
        accA[1] = MFMABF(a0l[1], bh0, accA[1]);
        accB[0] = MFMABF(a1l[0], bh1, accB[0]);
        accB[1] = MFMABF(a1l[1], bh1, accB[1]);
        accA[0] = MFMABF(a0h[0], bl0, accA[0]);
        accA[1] = MFMABF(a0h[1], bl0, accA[1]);
        accB[0] = MFMABF(a1h[0], bl1, accB[0]);
        accB[1] = MFMABF(a1h[1], bl1, accB[1]);

        const int code = tile * 16 + m;
        #pragma unroll
        for (int g = 0; g < 2; ++g) {
            #pragma unroll
            for (int r = 0; r < 4; ++r) {
                const float d = fmaf(-2.0f, accA[g][r] + accB[g][r], e2v);
                const int pl = w * 32 + g * 16 + quad * 4 + r;
                if (d < bd[g][r]) {
                    if (bd[g][r] < d + MARG) {              // near-tie supersession
                        const int slot = atomicAdd(&cand_cnt, 1);
                        if (slot < CAND_CAP) {
                            cand_pc[slot] = (pl << 16) | bi[g][r];
                            cand_d[slot] = bd[g][r];
                        }
                    }
                    bd[g][r] = d; bi[g][r] = code;
                } else if (d < bd[g][r] + MARG) {           // within margin of run-min
                    const int slot = atomicAdd(&cand_cnt, 1);
                    if (slot < CAND_CAP) {
                        cand_pc[slot] = (pl << 16) | code;
                        cand_d[slot] = d;
                    }
                }
            }
        }
        bh0 = nh0; bh1 = nh1; bl0 = nl0; bl1 = nl1;
    }

    // publish per-slot bests: point row = g*16 + quad*4 + r, col = m
    #pragma unroll
    for (int g = 0; g < 2; ++g)
        #pragma unroll
        for (int r = 0; r < 4; ++r) {
            best_d_s[w][g * 16 + quad * 4 + r][m] = bd[g][r];
            best_i_s[w][g * 16 + quad * 4 + r][m] = bi[g][r];
        }
    __syncthreads();

    // exact-rescore stage: one thread per point
    if (t < VQ_PTS) {
        const int p = t, ww = p >> 5, pi = p & 31;
        float dmin = 3.4e38f;
        #pragma unroll
        for (int c = 0; c < 16; ++c) dmin = fminf(dmin, best_d_s[ww][pi][c]);
        const float thr = dmin + MARG;

        float fbd = 3.4e38f; int fbi = 1 << 30;
        const float* xr = msg + (base + p) * OUT_DIM;   // still x
        #pragma unroll
        for (int c = 0; c < 16; ++c)
            if (best_d_s[ww][pi][c] <= thr)
                exact_upd(xr, cb, e2, best_i_s[ww][pi][c], fbd, fbi);
        const int L = min(cand_cnt, CAND_CAP);
        for (int l = 0; l < L; ++l) {
            const int pc = cand_pc[l];
            if ((pc >> 16) == p && cand_d[l] <= thr)
                exact_upd(xr, cb, e2, pc & 0xFFFF, fbd, fbi);
        }
        idx_sh[p] = fbi;
        idx_out[base + p] = (float)fbi;
    }
    __syncthreads();

    // gather q, write msg, accumulate loss (read-x / write-q same thread+addr)
    float lsum = 0.0f;
    float4* xg = (float4*)(msg + base * OUT_DIM);
    #pragma unroll
    for (int mm = 0; mm < 8; ++mm) {
        const int v = t + 256 * mm;
        const int p = v >> 4, k4 = v & 15;
        const int code = idx_sh[p];
        const float4 q = ((const float4*)(cb + (long)code * OUT_DIM))[k4];
        const float4 xv = xg[v];
        const float dx = q.x - xv.x, dy = q.y - xv.y;
        const float dz = q.z - xv.z, dw2 = q.w - xv.w;
        lsum += dx * dx + dy * dy + dz * dz + dw2 * dw2;
        xg[v] = q;
    }
    #pragma unroll
    for (int off = 32; off > 0; off >>= 1) lsum += __shfl_down(lsum, off, 64);
    if (lane == 0) wred[w] = lsum;
    __syncthreads();
    if (t == 0)
        atomicAdd(loss_out, (wred[0] + wred[1] + wred[2] + wred[3]) * LOSS_SCALE);
}

extern "C" void kernel_launch(void* const* d_in, const int* in_sizes, int n_in,
                              void* d_out, int out_size, void* d_ws, size_t ws_size,
                              hipStream_t stream) {
    const float* obs = (const float*)d_in[0];
    const float* W1  = (const float*)d_in[1];
    const float* b1  = (const float*)d_in[2];
    const float* W2  = (const float*)d_in[3];
    const float* b2  = (const float*)d_in[4];
    const float* W3  = (const float*)d_in[5];
    const float* b3  = (const float*)d_in[6];
    const float* cb  = (const float*)d_in[7];

    float* out  = (float*)d_out;
    float* msg  = out;                        // also x staging
    float* idxf = out + MSG_ELEMS;
    float* loss = out + MSG_ELEMS + NPTS;

    char* ws = (char*)d_ws;
    float*          e2  = (float*)ws;                          // 8 KB
    unsigned short* cbh = (unsigned short*)(ws + 8192);        // 256 KB
    unsigned short* cbl = (unsigned short*)(ws + 270336);      // 256 KB
    _Float16* w1h = (_Float16*)(ws + 532480);                  // 16 KB
    _Float16* w1l = (_Float16*)(ws + 548864);                  // 16 KB
    _Float16* w2h = (_Float16*)(ws + 565248);                  // 8 KB
    _Float16* w2l = (_Float16*)(ws + 573440);                  // 8 KB
    _Float16* w3h = (_Float16*)(ws + 581632);                  // 8 KB
    _Float16* w3l = (_Float16*)(ws + 589824);                  // 8 KB

    zero_loss_kernel<<<1, 1, 0, stream>>>(loss);
    e2_kernel<<<CB_N / 256, 256, 0, stream>>>(cb, e2);
    prep_cb<<<16, 256, 0, stream>>>(cb, cbh, cbl);
    prep_w<<<8, 256, 0, stream>>>(W1, W2, W3, w1h, w1l, w2h, w2l, w3h, w3l);
    mlp_mfma<<<NPTS / 64, 256, 0, stream>>>(obs, b1, b2, b3,
                                            w1h, w1l, w2h, w2l, w3h, w3l, msg);
    vq_mfma<<<NPTS / VQ_PTS, 256, 0, stream>>>(cb, cbh, cbl, e2, msg, idxf, loss);
}

// Round 2
// 244.788 us; speedup vs baseline: 1.2392x; 1.2392x over previous
//
#include <hip/hip_runtime.h>

// VQSpeaker: obs[32,2048,128] -> 3-layer MLP -> x[65536,64] -> VQ argmin over
// codebook[2048,64] -> (msg = codebook[idx], idx, cmt_loss).
//
// Round 10: vq = R3 structure (16 pts/wave, 1024 blocks = 4 blocks/CU).
//           KEY CHANGE: __launch_bounds__(256, 4) on mlp_mfma + vq_mfma.
//           R9's counters showed VGPR_Count=64 for a loop needing ~100+ regs
//           -> compiler was spilling the inner-loop B-frags/accs to scratch
//           (~3800 cyc/tile latency, MfmaUtil 10%, all pipes idle). The
//           min-waves=4 bound raises the VGPR budget to 128/wave (4 waves/SIMD
//           target), fitting the working set with zero scratch.
//
// d_out layout (float32): msg[4194304] | idx[65536] (as float) | loss[1]
// d_ws: e2[2048] | cbh bf16 256KB | cbl bf16 256KB | w1h/w1l 16KB ea |
//       w2h/w2l/w3h/w3l 8KB ea   (total ~584 KB)

#define NPTS    65536
#define IN_DIM  128
#define HID     64
#define OUT_DIM 64
#define CB_N    2048
#define MSG_ELEMS (NPTS * OUT_DIM)
#define LOSS_SCALE (1.0f / 4194304.0f)
#define MARG 0.5f          // R3-proven screening margin
#define CAND_CAP 512

typedef __attribute__((ext_vector_type(8))) short short8;
typedef _Float16 half8 __attribute__((ext_vector_type(8)));
typedef __attribute__((ext_vector_type(4))) float f32x4;

__device__ __forceinline__ unsigned short f2bf(float f) {
    unsigned u = __float_as_uint(f);
    u += 0x7FFF + ((u >> 16) & 1);          // RN-even to bf16
    return (unsigned short)(u >> 16);
}
__device__ __forceinline__ float bf2f(unsigned short h) {
    return __uint_as_float((unsigned)h << 16);
}

__global__ void zero_loss_kernel(float* __restrict__ loss) { *loss = 0.0f; }

__global__ __launch_bounds__(256) void e2_kernel(
    const float* __restrict__ codebook, float* __restrict__ e2)
{
    const int c = blockIdx.x * 256 + threadIdx.x;
    const float4* row = (const float4*)(codebook + (long)c * OUT_DIM);
    float s = 0.0f;
    #pragma unroll
    for (int m = 0; m < 16; ++m) {
        const float4 v = row[m];
        s += v.x * v.x + v.y * v.y + v.z * v.z + v.w * v.w;
    }
    e2[c] = s;
}

// Permute codebook into MFMA B-fragment order, split hi/lo bf16 (R3-verified).
__global__ __launch_bounds__(256) void prep_cb(
    const float* __restrict__ cb,
    unsigned short* __restrict__ cbh, unsigned short* __restrict__ cbl)
{
    const int id = blockIdx.x * 256 + threadIdx.x;  // 0..4095: (code n, half h)
    const int n = id >> 1, h = id & 1;
    const int t = n >> 4, l15 = n & 15;
    const float* src = cb + (long)n * OUT_DIM + h * 32;
    #pragma unroll
    for (int quad = 0; quad < 4; ++quad) {
        short8 hi, lo;
        #pragma unroll
        for (int j = 0; j < 8; ++j) {
            const float f = src[quad * 8 + j];
            const unsigned short hb = f2bf(f);
            hi[j] = (short)hb;
            lo[j] = (short)f2bf(f - bf2f(hb));
        }
        const long dst = ((long)(t * 2 + h) * 64 + quad * 16 + l15) * 8;
        *(short8*)(cbh + dst) = hi;
        *(short8*)(cbl + dst) = lo;
    }
}

// Permute W1/W2/W3 into MFMA B-frag order, fp16 hi/lo split.
// frag[lane][j] = W[kc*32 + (lane>>4)*8 + j][nt*16 + (lane&15)], frag = kc*4+nt
__global__ __launch_bounds__(256) void prep_w(
    const float* __restrict__ W1, const float* __restrict__ W2,
    const float* __restrict__ W3,
    _Float16* __restrict__ w1h, _Float16* __restrict__ w1l,
    _Float16* __restrict__ w2h, _Float16* __restrict__ w2l,
    _Float16* __restrict__ w3h, _Float16* __restrict__ w3l)
{
    const int id = blockIdx.x * 256 + threadIdx.x;   // 0..2047
    const int lane = id & 63;
    const int m = lane & 15, quad = lane >> 4;
    const float* W; _Float16 *dh, *dl; int frag;
    if (id < 1024)      { W = W1; dh = w1h; dl = w1l; frag = id >> 6; }          // 16 frags
    else if (id < 1536) { W = W2; dh = w2h; dl = w2l; frag = (id - 1024) >> 6; } // 8
    else                { W = W3; dh = w3h; dl = w3l; frag = (id - 1536) >> 6; } // 8
    const int kc = frag >> 2, nt = frag & 3;
    half8 hi, lo;
    #pragma unroll
    for (int j = 0; j < 8; ++j) {
        const float v = W[(long)(kc * 32 + quad * 8 + j) * 64 + nt * 16 + m];
        hi[j] = (_Float16)v;
        lo[j] = (_Float16)(v - (float)hi[j]);
    }
    const long dst = (long)(frag * 64 + lane) * 8;
    *(half8*)(dh + dst) = hi;
    *(half8*)(dl + dst) = lo;
}

#define MFMA16(A, B, C) __builtin_amdgcn_mfma_f32_16x16x32_f16(A, B, C, 0, 0, 0)

__device__ __forceinline__ void split16(const float* xs, half8& h, half8& l) {
    #pragma unroll
    for (int j = 0; j < 8; ++j) {
        h[j] = (_Float16)xs[j];
        l[j] = (_Float16)(xs[j] - (float)h[j]);
    }
}

// ---------------- MLP via MFMA: 64 pts/block, 256 thr = 4 waves -------------
// Wave w owns points w*16..w*16+15 end-to-end; LDS traffic is wave-local so
// no barriers until the final cross-wave coalesced store.
// launch_bounds(256,4): 128-VGPR budget (working set ~90) -> no scratch.
__global__ __launch_bounds__(256, 4) void mlp_mfma(
    const float* __restrict__ obs,
    const float* __restrict__ b1, const float* __restrict__ b2,
    const float* __restrict__ b3,
    const _Float16* __restrict__ w1h, const _Float16* __restrict__ w1l,
    const _Float16* __restrict__ w2h, const _Float16* __restrict__ w2l,
    const _Float16* __restrict__ w3h, const _Float16* __restrict__ w3l,
    float* __restrict__ xout)
{
    __shared__ float hbuf[64 * 68];     // stride 68: <=2-way banks (free)
    const int t = threadIdx.x, lane = t & 63, w = t >> 6;
    const int m = lane & 15, quad = lane >> 4;
    const long base = (long)blockIdx.x * 64;
    const int row0 = w * 16 + quad * 4;         // C-layout write rows (+r)
    const int arow_l = w * 16 + m;              // A-layout read row

    float bb1[4], bb2[4], bb3[4];
    #pragma unroll
    for (int nt = 0; nt < 4; ++nt) {
        bb1[nt] = b1[nt * 16 + m];
        bb2[nt] = b2[nt * 16 + m];
        bb3[nt] = b3[nt * 16 + m];
    }

    // ---- A-frags from obs (fp16 split), K = 128 -> 4 chunks ----
    const float* arow = obs + (base + w * 16 + m) * IN_DIM;
    half8 a1h[4], a1l[4];
    #pragma unroll
    for (int kc = 0; kc < 4; ++kc) {
        const float4 va = *(const float4*)(arow + kc * 32 + quad * 8);
        const float4 vb = *(const float4*)(arow + kc * 32 + quad * 8 + 4);
        const float xs[8] = {va.x, va.y, va.z, va.w, vb.x, vb.y, vb.z, vb.w};
        split16(xs, a1h[kc], a1l[kc]);
    }

    // ---- layer 1: [64x128]x[128x64] + b1, relu ----
    #pragma unroll
    for (int nt = 0; nt < 4; ++nt) {
        f32x4 acc = {0.0f, 0.0f, 0.0f, 0.0f};
        #pragma unroll
        for (int kc = 0; kc < 4; ++kc) {
            const long fo = (long)((kc * 4 + nt) * 64 + lane) * 8;
            const half8 wh = *(const half8*)(w1h + fo);
            const half8 wl = *(const half8*)(w1l + fo);
            acc = MFMA16(a1h[kc], wh, acc);
            acc = MFMA16(a1l[kc], wh, acc);
            acc = MFMA16(a1h[kc], wl, acc);
        }
        #pragma unroll
        for (int r = 0; r < 4; ++r) {
            const float v = acc[r] + bb1[nt];
            hbuf[(row0 + r) * 68 + nt * 16 + m] = v > 0.0f ? v : 0.0f;
        }
    }

    // ---- layer 2: [64x64]x[64x64] + b2, relu (A re-split from LDS) ----
    half8 a2h[2], a2l[2];
    #pragma unroll
    for (int kc = 0; kc < 2; ++kc) {
        const float4 va = *(const float4*)&hbuf[arow_l * 68 + kc * 32 + quad * 8];
        const float4 vb = *(const float4*)&hbuf[arow_l * 68 + kc * 32 + quad * 8 + 4];
        const float xs[8] = {va.x, va.y, va.z, va.w, vb.x, vb.y, vb.z, vb.w};
        split16(xs, a2h[kc], a2l[kc]);
    }
    #pragma unroll
    for (int nt = 0; nt < 4; ++nt) {
        f32x4 acc = {0.0f, 0.0f, 0.0f, 0.0f};
        #pragma unroll
        for (int kc = 0; kc < 2; ++kc) {
            const long fo = (long)((kc * 4 + nt) * 64 + lane) * 8;
            const half8 wh = *(const half8*)(w2h + fo);
            const half8 wl = *(const half8*)(w2l + fo);
            acc = MFMA16(a2h[kc], wh, acc);
            acc = MFMA16(a2l[kc], wh, acc);
            acc = MFMA16(a2h[kc], wl, acc);
        }
        #pragma unroll
        for (int r = 0; r < 4; ++r) {
            const float v = acc[r] + bb2[nt];
            hbuf[(row0 + r) * 68 + nt * 16 + m] = v > 0.0f ? v : 0.0f;
        }
    }

    // ---- layer 3: [64x64]x[64x64] + b3 (no relu) ----
    half8 a3h[2], a3l[2];
    #pragma unroll
    for (int kc = 0; kc < 2; ++kc) {
        const float4 va = *(const float4*)&hbuf[arow_l * 68 + kc * 32 + quad * 8];
        const float4 vb = *(const float4*)&hbuf[arow_l * 68 + kc * 32 + quad * 8 + 4];
        const float xs[8] = {va.x, va.y, va.z, va.w, vb.x, vb.y, vb.z, vb.w};
        split16(xs, a3h[kc], a3l[kc]);
    }
    #pragma unroll
    for (int nt = 0; nt < 4; ++nt) {
        f32x4 acc = {0.0f, 0.0f, 0.0f, 0.0f};
        #pragma unroll
        for (int kc = 0; kc < 2; ++kc) {
            const long fo = (long)((kc * 4 + nt) * 64 + lane) * 8;
            const half8 wh = *(const half8*)(w3h + fo);
            const half8 wl = *(const half8*)(w3l + fo);
            acc = MFMA16(a3h[kc], wh, acc);
            acc = MFMA16(a3l[kc], wh, acc);
            acc = MFMA16(a3h[kc], wl, acc);
        }
        #pragma unroll
        for (int r = 0; r < 4; ++r)
            hbuf[(row0 + r) * 68 + nt * 16 + m] = acc[r] + bb3[nt];
    }
    __syncthreads();    // only cross-wave touch: coalesced store below

    float4* og = (float4*)(xout + base * OUT_DIM);
    #pragma unroll
    for (int mm = 0; mm < 4; ++mm) {
        const int v = t + 256 * mm;
        const int p = v >> 4, k4 = v & 15;
        og[v] = *(const float4*)&hbuf[p * 68 + k4 * 4];
    }
}

// exact fp32 distance update (R2/R3 proven numerics)
__device__ __forceinline__ void exact_upd(
    const float* __restrict__ xr, const float* __restrict__ cb,
    const float* __restrict__ e2, int n, float& bd, int& bi)
{
    const float4* xp = (const float4*)xr;
    const float4* cp = (const float4*)(cb + (long)n * OUT_DIM);
    float a0 = 0.0f, a1 = 0.0f;
    #pragma unroll
    for (int m = 0; m < 16; ++m) {
        const float4 xv = xp[m], cv = cp[m];
        a0 = fmaf(xv.x, cv.x, a0); a1 = fmaf(xv.y, cv.y, a1);
        a0 = fmaf(xv.z, cv.z, a0); a1 = fmaf(xv.w, cv.w, a1);
    }
    const float ex = fmaf(-2.0f, a0 + a1, e2[n]);
    if (ex < bd || (ex == bd && n < bi)) { bd = ex; bi = n; }
}

// ---------------- VQ via MFMA: R3 structure, 16 pts/wave, 1024 blocks -------
// launch_bounds(256,4): 128-VGPR budget (working set ~96) -> no scratch,
// 4 blocks/CU co-resident (grid 1024 / 256 CU) -> 4 waves/SIMD latency hiding.
__global__ __launch_bounds__(256, 4) void vq_mfma(
    const float* __restrict__ cb,
    const unsigned short* __restrict__ cbhp,
    const unsigned short* __restrict__ cblp,
    const float* __restrict__ e2,
    float* __restrict__ msg,        // in: x, out: quantize
    float* __restrict__ idx_out,
    float* __restrict__ loss_out)
{
    __shared__ float best_d_s[4][16][16];   // [wave][pt][col]
    __shared__ int   best_i_s[4][16][16];
    __shared__ int   cand_pc[CAND_CAP];     // (p_local<<16) | code
    __shared__ float cand_d[CAND_CAP];
    __shared__ int   cand_cnt;
    __shared__ int   idx_sh[64];
    __shared__ float wred[4];

    const int t = threadIdx.x, lane = t & 63, w = t >> 6;
    const int m = lane & 15, quad = lane >> 4;
    const long base = (long)blockIdx.x * 64;

    if (t == 0) cand_cnt = 0;

    // A-frags: x[point = w*16 + m][k = quad*8 + j], halves k0=0/32. Built once.
    const float* xrow = msg + (base + w * 16 + m) * OUT_DIM;
    short8 a0h, a0l, a1h, a1l;
    {
        const float4 xa = *(const float4*)(xrow + quad * 8);
        const float4 xb = *(const float4*)(xrow + quad * 8 + 4);
        const float4 xc = *(const float4*)(xrow + 32 + quad * 8);
        const float4 xd = *(const float4*)(xrow + 32 + quad * 8 + 4);
        const float x0[8] = {xa.x, xa.y, xa.z, xa.w, xb.x, xb.y, xb.z, xb.w};
        const float x1[8] = {xc.x, xc.y, xc.z, xc.w, xd.x, xd.y, xd.z, xd.w};
        #pragma unroll
        for (int j = 0; j < 8; ++j) {
            unsigned short hb = f2bf(x0[j]);
            a0h[j] = (short)hb; a0l[j] = (short)f2bf(x0[j] - bf2f(hb));
            hb = f2bf(x1[j]);
            a1h[j] = (short)hb; a1l[j] = (short)f2bf(x1[j] - bf2f(hb));
        }
    }
    __syncthreads();   // cand_cnt visible

    float bd[4] = {3.4e38f, 3.4e38f, 3.4e38f, 3.4e38f};
    int   bi[4] = {0, 0, 0, 0};

    // register double-buffered B-frags
    long toff = (long)lane * 8;
    short8 bh0 = *(const short8*)(cbhp + toff);
    short8 bh1 = *(const short8*)(cbhp + toff + 512);
    short8 bl0 = *(const short8*)(cblp + toff);
    short8 bl1 = *(const short8*)(cblp + toff + 512);

    for (int tile = 0; tile < 128; ++tile) {
        const int nt = (tile + 1 < 128) ? tile + 1 : 127;
        const long noff = (long)nt * 1024 + (long)lane * 8;
        const short8 nh0 = *(const short8*)(cbhp + noff);
        const short8 nh1 = *(const short8*)(cbhp + noff + 512);
        const short8 nl0 = *(const short8*)(cblp + noff);
        const short8 nl1 = *(const short8*)(cblp + noff + 512);
        const float e2v = e2[tile * 16 + m];

        f32x4 acc0 = {0.0f, 0.0f, 0.0f, 0.0f};
        f32x4 acc1 = {0.0f, 0.0f, 0.0f, 0.0f};
        acc0 = __builtin_amdgcn_mfma_f32_16x16x32_bf16(a0h, bh0, acc0, 0, 0, 0);
        acc1 = __builtin_amdgcn_mfma_f32_16x16x32_bf16(a1h, bh1, acc1, 0, 0, 0);
        acc0 = __builtin_amdgcn_mfma_f32_16x16x32_bf16(a0l, bh0, acc0, 0, 0, 0);
        acc1 = __builtin_amdgcn_mfma_f32_16x16x32_bf16(a1l, bh1, acc1, 0, 0, 0);
        acc0 = __builtin_amdgcn_mfma_f32_16x16x32_bf16(a0h, bl0, acc0, 0, 0, 0);
        acc1 = __builtin_amdgcn_mfma_f32_16x16x32_bf16(a1h, bl1, acc1, 0, 0, 0);

        const int code = tile * 16 + m;
        #pragma unroll
        for (int r = 0; r < 4; ++r) {
            const float d = fmaf(-2.0f, acc0[r] + acc1[r], e2v);
            if (d < bd[r]) {
                if (bd[r] < d + MARG) {                 // near-tie supersession
                    const int slot = atomicAdd(&cand_cnt, 1);
                    if (slot < CAND_CAP) {
                        cand_pc[slot] = ((w * 16 + quad * 4 + r) << 16) | bi[r];
                        cand_d[slot] = bd[r];
                    }
                }
                bd[r] = d; bi[r] = code;
            } else if (d < bd[r] + MARG) {              // within margin of run-min
                const int slot = atomicAdd(&cand_cnt, 1);
                if (slot < CAND_CAP) {
                    cand_pc[slot] = ((w * 16 + quad * 4 + r) << 16) | code;
                    cand_d[slot] = d;
                }
            }
        }
        bh0 = nh0; bh1 = nh1; bl0 = nl0; bl1 = nl1;
    }

    // publish per-slot bests: point row = quad*4 + r, col = m
    #pragma unroll
    for (int r = 0; r < 4; ++r) {
        best_d_s[w][quad * 4 + r][m] = bd[r];
        best_i_s[w][quad * 4 + r][m] = bi[r];
    }
    __syncthreads();

    // exact-rescore stage: one thread per point
    if (t < 64) {
        const int p = t, ww = p >> 4, pi = p & 15;
        float dmin = 3.4e38f;
        #pragma unroll
        for (int c = 0; c < 16; ++c) dmin = fminf(dmin, best_d_s[ww][pi][c]);
        const float thr = dmin + MARG;

        float fbd = 3.4e38f; int fbi = 1 << 30;
        const float* xr = msg + (base + p) * OUT_DIM;   // still x
        #pragma unroll
        for (int c = 0; c < 16; ++c)
            if (best_d_s[ww][pi][c] <= thr)
                exact_upd(xr, cb, e2, best_i_s[ww][pi][c], fbd, fbi);
        const int L = min(cand_cnt, CAND_CAP);
        for (int l = 0; l < L; ++l) {
            const int pc = cand_pc[l];
            if ((pc >> 16) == p && cand_d[l] <= thr)
                exact_upd(xr, cb, e2, pc & 0xFFFF, fbd, fbi);
        }
        idx_sh[p] = fbi;
        idx_out[base + p] = (float)fbi;
    }
    __syncthreads();

    // gather q, write msg, accumulate loss (read-x / write-q same thread+addr)
    float lsum = 0.0f;
    float4* xg = (float4*)(msg + base * OUT_DIM);
    #pragma unroll
    for (int mm = 0; mm < 4; ++mm) {
        const int v = t + 256 * mm;
        const int p = v >> 4, k4 = v & 15;
        const int code = idx_sh[p];
        const float4 q = ((const float4*)(cb + (long)code * OUT_DIM))[k4];
        const float4 xv = xg[v];
        const float dx = q.x - xv.x, dy = q.y - xv.y;
        const float dz = q.z - xv.z, dw2 = q.w - xv.w;
        lsum += dx * dx + dy * dy + dz * dz + dw2 * dw2;
        xg[v] = q;
    }
    #pragma unroll
    for (int off = 32; off > 0; off >>= 1) lsum += __shfl_down(lsum, off, 64);
    if (lane == 0) wred[w] = lsum;
    __syncthreads();
    if (t == 0)
        atomicAdd(loss_out, (wred[0] + wred[1] + wred[2] + wred[3]) * LOSS_SCALE);
}

extern "C" void kernel_launch(void* const* d_in, const int* in_sizes, int n_in,
                              void* d_out, int out_size, void* d_ws, size_t ws_size,
                              hipStream_t stream) {
    const float* obs = (const float*)d_in[0];
    const float* W1  = (const float*)d_in[1];
    const float* b1  = (const float*)d_in[2];
    const float* W2  = (const float*)d_in[3];
    const float* b2  = (const float*)d_in[4];
    const float* W3  = (const float*)d_in[5];
    const float* b3  = (const float*)d_in[6];
    const float* cb  = (const float*)d_in[7];

    float* out  = (float*)d_out;
    float* msg  = out;                        // also x staging
    float* idxf = out + MSG_ELEMS;
    float* loss = out + MSG_ELEMS + NPTS;

    char* ws = (char*)d_ws;
    float*          e2  = (float*)ws;                          // 8 KB
    unsigned short* cbh = (unsigned short*)(ws + 8192);        // 256 KB
    unsigned short* cbl = (unsigned short*)(ws + 270336);      // 256 KB
    _Float16* w1h = (_Float16*)(ws + 532480);                  // 16 KB
    _Float16* w1l = (_Float16*)(ws + 548864);                  // 16 KB
    _Float16* w2h = (_Float16*)(ws + 565248);                  // 8 KB
    _Float16* w2l = (_Float16*)(ws + 573440);                  // 8 KB
    _Float16* w3h = (_Float16*)(ws + 581632);                  // 8 KB
    _Float16* w3l = (_Float16*)(ws + 589824);                  // 8 KB

    zero_loss_kernel<<<1, 1, 0, stream>>>(loss);
    e2_kernel<<<CB_N / 256, 256, 0, stream>>>(cb, e2);
    prep_cb<<<16, 256, 0, stream>>>(cb, cbh, cbl);
    prep_w<<<8, 256, 0, stream>>>(W1, W2, W3, w1h, w1l, w2h, w2l, w3h, w3l);
    mlp_mfma<<<NPTS / 64, 256, 0, stream>>>(obs, b1, b2, b3,
                                            w1h, w1l, w2h, w2l, w3h, w3l, msg);
    vq_mfma<<<NPTS / 64, 256, 0, stream>>>(cb, cbh, cbl, e2, msg, idxf, loss);
}

// Round 3
// 234.554 us; speedup vs baseline: 1.2932x; 1.0436x over previous
//
#include <hip/hip_runtime.h>

// VQSpeaker: obs[32,2048,128] -> 3-layer MLP -> x[65536,64] -> VQ argmin over
// codebook[2048,64] -> (msg = codebook[idx], idx, cmt_loss).
//
// Round 11: FUSED mlp+vq. Both had identical block geometry (64 pts/block,
//           4 waves, wave-local rows), so the MLP now writes x into LDS hbuf
//           and the VQ phase (R10-verbatim tile loop, screening, rescore,
//           loss) reads x from LDS. Eliminates the 16MB x write + 16MB x read
//           round-trip, one kernel launch/drain, and the duplicate x load.
//           msg is now write-only. launch_bounds(256,4) kept (R10-proven).
//
// d_out layout (float32): msg[4194304] | idx[65536] (as float) | loss[1]
// d_ws: e2[2048] | cbh bf16 256KB | cbl bf16 256KB | w1h/w1l 16KB ea |
//       w2h/w2l/w3h/w3l 8KB ea   (total ~584 KB)

#define NPTS    65536
#define IN_DIM  128
#define HID     64
#define OUT_DIM 64
#define CB_N    2048
#define MSG_ELEMS (NPTS * OUT_DIM)
#define LOSS_SCALE (1.0f / 4194304.0f)
#define MARG 0.5f          // R3-proven screening margin
#define CAND_CAP 512

typedef __attribute__((ext_vector_type(8))) short short8;
typedef _Float16 half8 __attribute__((ext_vector_type(8)));
typedef __attribute__((ext_vector_type(4))) float f32x4;

__device__ __forceinline__ unsigned short f2bf(float f) {
    unsigned u = __float_as_uint(f);
    u += 0x7FFF + ((u >> 16) & 1);          // RN-even to bf16
    return (unsigned short)(u >> 16);
}
__device__ __forceinline__ float bf2f(unsigned short h) {
    return __uint_as_float((unsigned)h << 16);
}

__global__ void zero_loss_kernel(float* __restrict__ loss) { *loss = 0.0f; }

__global__ __launch_bounds__(256) void e2_kernel(
    const float* __restrict__ codebook, float* __restrict__ e2)
{
    const int c = blockIdx.x * 256 + threadIdx.x;
    const float4* row = (const float4*)(codebook + (long)c * OUT_DIM);
    float s = 0.0f;
    #pragma unroll
    for (int m = 0; m < 16; ++m) {
        const float4 v = row[m];
        s += v.x * v.x + v.y * v.y + v.z * v.z + v.w * v.w;
    }
    e2[c] = s;
}

// Permute codebook into MFMA B-fragment order, split hi/lo bf16 (R3-verified).
__global__ __launch_bounds__(256) void prep_cb(
    const float* __restrict__ cb,
    unsigned short* __restrict__ cbh, unsigned short* __restrict__ cbl)
{
    const int id = blockIdx.x * 256 + threadIdx.x;  // 0..4095: (code n, half h)
    const int n = id >> 1, h = id & 1;
    const int t = n >> 4, l15 = n & 15;
    const float* src = cb + (long)n * OUT_DIM + h * 32;
    #pragma unroll
    for (int quad = 0; quad < 4; ++quad) {
        short8 hi, lo;
        #pragma unroll
        for (int j = 0; j < 8; ++j) {
            const float f = src[quad * 8 + j];
            const unsigned short hb = f2bf(f);
            hi[j] = (short)hb;
            lo[j] = (short)f2bf(f - bf2f(hb));
        }
        const long dst = ((long)(t * 2 + h) * 64 + quad * 16 + l15) * 8;
        *(short8*)(cbh + dst) = hi;
        *(short8*)(cbl + dst) = lo;
    }
}

// Permute W1/W2/W3 into MFMA B-frag order, fp16 hi/lo split.
// frag[lane][j] = W[kc*32 + (lane>>4)*8 + j][nt*16 + (lane&15)], frag = kc*4+nt
__global__ __launch_bounds__(256) void prep_w(
    const float* __restrict__ W1, const float* __restrict__ W2,
    const float* __restrict__ W3,
    _Float16* __restrict__ w1h, _Float16* __restrict__ w1l,
    _Float16* __restrict__ w2h, _Float16* __restrict__ w2l,
    _Float16* __restrict__ w3h, _Float16* __restrict__ w3l)
{
    const int id = blockIdx.x * 256 + threadIdx.x;   // 0..2047
    const int lane = id & 63;
    const int m = lane & 15, quad = lane >> 4;
    const float* W; _Float16 *dh, *dl; int frag;
    if (id < 1024)      { W = W1; dh = w1h; dl = w1l; frag = id >> 6; }          // 16 frags
    else if (id < 1536) { W = W2; dh = w2h; dl = w2l; frag = (id - 1024) >> 6; } // 8
    else                { W = W3; dh = w3h; dl = w3l; frag = (id - 1536) >> 6; } // 8
    const int kc = frag >> 2, nt = frag & 3;
    half8 hi, lo;
    #pragma unroll
    for (int j = 0; j < 8; ++j) {
        const float v = W[(long)(kc * 32 + quad * 8 + j) * 64 + nt * 16 + m];
        hi[j] = (_Float16)v;
        lo[j] = (_Float16)(v - (float)hi[j]);
    }
    const long dst = (long)(frag * 64 + lane) * 8;
    *(half8*)(dh + dst) = hi;
    *(half8*)(dl + dst) = lo;
}

#define MFMA16(A, B, C) __builtin_amdgcn_mfma_f32_16x16x32_f16(A, B, C, 0, 0, 0)

__device__ __forceinline__ void split16(const float* xs, half8& h, half8& l) {
    #pragma unroll
    for (int j = 0; j < 8; ++j) {
        h[j] = (_Float16)xs[j];
        l[j] = (_Float16)(xs[j] - (float)h[j]);
    }
}

// exact fp32 distance update (R2/R3 proven numerics); xr may be LDS.
__device__ __forceinline__ void exact_upd(
    const float* xr, const float* __restrict__ cb,
    const float* __restrict__ e2, int n, float& bd, int& bi)
{
    const float4* xp = (const float4*)xr;
    const float4* cp = (const float4*)(cb + (long)n * OUT_DIM);
    float a0 = 0.0f, a1 = 0.0f;
    #pragma unroll
    for (int m = 0; m < 16; ++m) {
        const float4 xv = xp[m], cv = cp[m];
        a0 = fmaf(xv.x, cv.x, a0); a1 = fmaf(xv.y, cv.y, a1);
        a0 = fmaf(xv.z, cv.z, a0); a1 = fmaf(xv.w, cv.w, a1);
    }
    const float ex = fmaf(-2.0f, a0 + a1, e2[n]);
    if (ex < bd || (ex == bd && n < bi)) { bd = ex; bi = n; }
}

// ---------------- FUSED: MLP (wave-local, x -> LDS) + VQ (R10-verbatim) ----
// 64 pts/block, 4 waves; wave w owns points w*16..w*16+15 through the MLP and
// the VQ tile scan. x never touches global memory.
__global__ __launch_bounds__(256, 4) void fused_mlp_vq(
    const float* __restrict__ obs,
    const float* __restrict__ b1, const float* __restrict__ b2,
    const float* __restrict__ b3,
    const _Float16* __restrict__ w1h, const _Float16* __restrict__ w1l,
    const _Float16* __restrict__ w2h, const _Float16* __restrict__ w2l,
    const _Float16* __restrict__ w3h, const _Float16* __restrict__ w3l,
    const float* __restrict__ cb,
    const unsigned short* __restrict__ cbhp,
    const unsigned short* __restrict__ cblp,
    const float* __restrict__ e2,
    float* __restrict__ msg,        // out only: quantize
    float* __restrict__ idx_out,
    float* __restrict__ loss_out)
{
    __shared__ float hbuf[64 * 68];         // mlp scratch, then x[64][64] @68
    __shared__ float best_d_s[4][16][16];   // [wave][pt][col]
    __shared__ int   best_i_s[4][16][16];
    __shared__ int   cand_pc[CAND_CAP];     // (p_local<<16) | code
    __shared__ float cand_d[CAND_CAP];
    __shared__ int   cand_cnt;
    __shared__ int   idx_sh[64];
    __shared__ float wred[4];

    const int t = threadIdx.x, lane = t & 63, w = t >> 6;
    const int m = lane & 15, quad = lane >> 4;
    const long base = (long)blockIdx.x * 64;
    const int row0 = w * 16 + quad * 4;         // C-layout write rows (+r)
    const int arow_l = w * 16 + m;              // A-layout read row

    if (t == 0) cand_cnt = 0;

    // ================= MLP phase (R10 mlp_mfma, wave-local) =================
    {
        float bb1[4], bb2[4], bb3[4];
        #pragma unroll
        for (int nt = 0; nt < 4; ++nt) {
            bb1[nt] = b1[nt * 16 + m];
            bb2[nt] = b2[nt * 16 + m];
            bb3[nt] = b3[nt * 16 + m];
        }

        // A-frags from obs (fp16 split), K = 128 -> 4 chunks
        const float* arow = obs + (base + w * 16 + m) * IN_DIM;
        half8 a1h[4], a1l[4];
        #pragma unroll
        for (int kc = 0; kc < 4; ++kc) {
            const float4 va = *(const float4*)(arow + kc * 32 + quad * 8);
            const float4 vb = *(const float4*)(arow + kc * 32 + quad * 8 + 4);
            const float xs[8] = {va.x, va.y, va.z, va.w, vb.x, vb.y, vb.z, vb.w};
            split16(xs, a1h[kc], a1l[kc]);
        }

        // layer 1: [64x128]x[128x64] + b1, relu
        #pragma unroll
        for (int nt = 0; nt < 4; ++nt) {
            f32x4 acc = {0.0f, 0.0f, 0.0f, 0.0f};
            #pragma unroll
            for (int kc = 0; kc < 4; ++kc) {
                const long fo = (long)((kc * 4 + nt) * 64 + lane) * 8;
                const half8 wh = *(const half8*)(w1h + fo);
                const half8 wl = *(const half8*)(w1l + fo);
                acc = MFMA16(a1h[kc], wh, acc);
                acc = MFMA16(a1l[kc], wh, acc);
                acc = MFMA16(a1h[kc], wl, acc);
            }
            #pragma unroll
            for (int r = 0; r < 4; ++r) {
                const float v = acc[r] + bb1[nt];
                hbuf[(row0 + r) * 68 + nt * 16 + m] = v > 0.0f ? v : 0.0f;
            }
        }

        // layer 2: [64x64]x[64x64] + b2, relu (A re-split from LDS)
        half8 a2h[2], a2l[2];
        #pragma unroll
        for (int kc = 0; kc < 2; ++kc) {
            const float4 va = *(const float4*)&hbuf[arow_l * 68 + kc * 32 + quad * 8];
            const float4 vb = *(const float4*)&hbuf[arow_l * 68 + kc * 32 + quad * 8 + 4];
            const float xs[8] = {va.x, va.y, va.z, va.w, vb.x, vb.y, vb.z, vb.w};
            split16(xs, a2h[kc], a2l[kc]);
        }
        #pragma unroll
        for (int nt = 0; nt < 4; ++nt) {
            f32x4 acc = {0.0f, 0.0f, 0.0f, 0.0f};
            #pragma unroll
            for (int kc = 0; kc < 2; ++kc) {
                const long fo = (long)((kc * 4 + nt) * 64 + lane) * 8;
                const half8 wh = *(const half8*)(w2h + fo);
                const half8 wl = *(const half8*)(w2l + fo);
                acc = MFMA16(a2h[kc], wh, acc);
                acc = MFMA16(a2l[kc], wh, acc);
                acc = MFMA16(a2h[kc], wl, acc);
            }
            #pragma unroll
            for (int r = 0; r < 4; ++r) {
                const float v = acc[r] + bb2[nt];
                hbuf[(row0 + r) * 68 + nt * 16 + m] = v > 0.0f ? v : 0.0f;
            }
        }

        // layer 3: [64x64]x[64x64] + b3 (no relu) -> x rows in hbuf
        half8 a3h[2], a3l[2];
        #pragma unroll
        for (int kc = 0; kc < 2; ++kc) {
            const float4 va = *(const float4*)&hbuf[arow_l * 68 + kc * 32 + quad * 8];
            const float4 vb = *(const float4*)&hbuf[arow_l * 68 + kc * 32 + quad * 8 + 4];
            const float xs[8] = {va.x, va.y, va.z, va.w, vb.x, vb.y, vb.z, vb.w};
            split16(xs, a3h[kc], a3l[kc]);
        }
        #pragma unroll
        for (int nt = 0; nt < 4; ++nt) {
            f32x4 acc = {0.0f, 0.0f, 0.0f, 0.0f};
            #pragma unroll
            for (int kc = 0; kc < 2; ++kc) {
                const long fo = (long)((kc * 4 + nt) * 64 + lane) * 8;
                const half8 wh = *(const half8*)(w3h + fo);
                const half8 wl = *(const half8*)(w3l + fo);
                acc = MFMA16(a3h[kc], wh, acc);
                acc = MFMA16(a3l[kc], wh, acc);
                acc = MFMA16(a3h[kc], wl, acc);
            }
            #pragma unroll
            for (int r = 0; r < 4; ++r)
                hbuf[(row0 + r) * 68 + nt * 16 + m] = acc[r] + bb3[nt];
        }
    }

    // ================= VQ phase (R10 vq_mfma, verbatim tile loop) ===========
    // A-frags: x[point = w*16 + m][k = quad*8 + j] from LDS (wave-local rows).
    const float* xrow = &hbuf[(w * 16 + m) * 68];
    short8 a0h, a0l, a1h, a1l;
    {
        const float4 xa = *(const float4*)(xrow + quad * 8);
        const float4 xb = *(const float4*)(xrow + quad * 8 + 4);
        const float4 xc = *(const float4*)(xrow + 32 + quad * 8);
        const float4 xd = *(const float4*)(xrow + 32 + quad * 8 + 4);
        const float x0[8] = {xa.x, xa.y, xa.z, xa.w, xb.x, xb.y, xb.z, xb.w};
        const float x1[8] = {xc.x, xc.y, xc.z, xc.w, xd.x, xd.y, xd.z, xd.w};
        #pragma unroll
        for (int j = 0; j < 8; ++j) {
            unsigned short hb = f2bf(x0[j]);
            a0h[j] = (short)hb; a0l[j] = (short)f2bf(x0[j] - bf2f(hb));
            hb = f2bf(x1[j]);
            a1h[j] = (short)hb; a1l[j] = (short)f2bf(x1[j] - bf2f(hb));
        }
    }
    __syncthreads();   // cand_cnt + all hbuf x rows visible block-wide

    float bd[4] = {3.4e38f, 3.4e38f, 3.4e38f, 3.4e38f};
    int   bi[4] = {0, 0, 0, 0};

    // register double-buffered B-frags
    long toff = (long)lane * 8;
    short8 bh0 = *(const short8*)(cbhp + toff);
    short8 bh1 = *(const short8*)(cbhp + toff + 512);
    short8 bl0 = *(const short8*)(cblp + toff);
    short8 bl1 = *(const short8*)(cblp + toff + 512);

    for (int tile = 0; tile < 128; ++tile) {
        const int nt = (tile + 1 < 128) ? tile + 1 : 127;
        const long noff = (long)nt * 1024 + (long)lane * 8;
        const short8 nh0 = *(const short8*)(cbhp + noff);
        const short8 nh1 = *(const short8*)(cbhp + noff + 512);
        const short8 nl0 = *(const short8*)(cblp + noff);
        const short8 nl1 = *(const short8*)(cblp + noff + 512);
        const float e2v = e2[tile * 16 + m];

        f32x4 acc0 = {0.0f, 0.0f, 0.0f, 0.0f};
        f32x4 acc1 = {0.0f, 0.0f, 0.0f, 0.0f};
        acc0 = __builtin_amdgcn_mfma_f32_16x16x32_bf16(a0h, bh0, acc0, 0, 0, 0);
        acc1 = __builtin_amdgcn_mfma_f32_16x16x32_bf16(a1h, bh1, acc1, 0, 0, 0);
        acc0 = __builtin_amdgcn_mfma_f32_16x16x32_bf16(a0l, bh0, acc0, 0, 0, 0);
        acc1 = __builtin_amdgcn_mfma_f32_16x16x32_bf16(a1l, bh1, acc1, 0, 0, 0);
        acc0 = __builtin_amdgcn_mfma_f32_16x16x32_bf16(a0h, bl0, acc0, 0, 0, 0);
        acc1 = __builtin_amdgcn_mfma_f32_16x16x32_bf16(a1h, bl1, acc1, 0, 0, 0);

        const int code = tile * 16 + m;
        #pragma unroll
        for (int r = 0; r < 4; ++r) {
            const float d = fmaf(-2.0f, acc0[r] + acc1[r], e2v);
            if (d < bd[r]) {
                if (bd[r] < d + MARG) {                 // near-tie supersession
                    const int slot = atomicAdd(&cand_cnt, 1);
                    if (slot < CAND_CAP) {
                        cand_pc[slot] = ((w * 16 + quad * 4 + r) << 16) | bi[r];
                        cand_d[slot] = bd[r];
                    }
                }
                bd[r] = d; bi[r] = code;
            } else if (d < bd[r] + MARG) {              // within margin of run-min
                const int slot = atomicAdd(&cand_cnt, 1);
                if (slot < CAND_CAP) {
                    cand_pc[slot] = ((w * 16 + quad * 4 + r) << 16) | code;
                    cand_d[slot] = d;
                }
            }
        }
        bh0 = nh0; bh1 = nh1; bl0 = nl0; bl1 = nl1;
    }

    // publish per-slot bests: point row = quad*4 + r, col = m
    #pragma unroll
    for (int r = 0; r < 4; ++r) {
        best_d_s[w][quad * 4 + r][m] = bd[r];
        best_i_s[w][quad * 4 + r][m] = bi[r];
    }
    __syncthreads();

    // exact-rescore stage: one thread per point (x read from LDS)
    if (t < 64) {
        const int p = t, ww = p >> 4, pi = p & 15;
        float dmin = 3.4e38f;
        #pragma unroll
        for (int c = 0; c < 16; ++c) dmin = fminf(dmin, best_d_s[ww][pi][c]);
        const float thr = dmin + MARG;

        float fbd = 3.4e38f; int fbi = 1 << 30;
        const float* xr = &hbuf[p * 68];
        #pragma unroll
        for (int c = 0; c < 16; ++c)
            if (best_d_s[ww][pi][c] <= thr)
                exact_upd(xr, cb, e2, best_i_s[ww][pi][c], fbd, fbi);
        const int L = min(cand_cnt, CAND_CAP);
        for (int l = 0; l < L; ++l) {
            const int pc = cand_pc[l];
            if ((pc >> 16) == p && cand_d[l] <= thr)
                exact_upd(xr, cb, e2, pc & 0xFFFF, fbd, fbi);
        }
        idx_sh[p] = fbi;
        idx_out[base + p] = (float)fbi;
    }
    __syncthreads();

    // gather q, write msg (write-only), accumulate loss (x from LDS)
    float lsum = 0.0f;
    float4* mg = (float4*)(msg + base * OUT_DIM);
    #pragma unroll
    for (int mm = 0; mm < 4; ++mm) {
        const int v = t + 256 * mm;
        const int p = v >> 4, k4 = v & 15;
        const int code = idx_sh[p];
        const float4 q = ((const float4*)(cb + (long)code * OUT_DIM))[k4];
        const float4 xv = *(const float4*)&hbuf[p * 68 + k4 * 4];
        const float dx = q.x - xv.x, dy = q.y - xv.y;
        const float dz = q.z - xv.z, dw2 = q.w - xv.w;
        lsum += dx * dx + dy * dy + dz * dz + dw2 * dw2;
        mg[v] = q;
    }
    #pragma unroll
    for (int off = 32; off > 0; off >>= 1) lsum += __shfl_down(lsum, off, 64);
    if (lane == 0) wred[w] = lsum;
    __syncthreads();
    if (t == 0)
        atomicAdd(loss_out, (wred[0] + wred[1] + wred[2] + wred[3]) * LOSS_SCALE);
}

extern "C" void kernel_launch(void* const* d_in, const int* in_sizes, int n_in,
                              void* d_out, int out_size, void* d_ws, size_t ws_size,
                              hipStream_t stream) {
    const float* obs = (const float*)d_in[0];
    const float* W1  = (const float*)d_in[1];
    const float* b1  = (const float*)d_in[2];
    const float* W2  = (const float*)d_in[3];
    const float* b2  = (const float*)d_in[4];
    const float* W3  = (const float*)d_in[5];
    const float* b3  = (const float*)d_in[6];
    const float* cb  = (const float*)d_in[7];

    float* out  = (float*)d_out;
    float* msg  = out;
    float* idxf = out + MSG_ELEMS;
    float* loss = out + MSG_ELEMS + NPTS;

    char* ws = (char*)d_ws;
    float*          e2  = (float*)ws;                          // 8 KB
    unsigned short* cbh = (unsigned short*)(ws + 8192);        // 256 KB
    unsigned short* cbl = (unsigned short*)(ws + 270336);      // 256 KB
    _Float16* w1h = (_Float16*)(ws + 532480);                  // 16 KB
    _Float16* w1l = (_Float16*)(ws + 548864);                  // 16 KB
    _Float16* w2h = (_Float16*)(ws + 565248);                  // 8 KB
    _Float16* w2l = (_Float16*)(ws + 573440);                  // 8 KB
    _Float16* w3h = (_Float16*)(ws + 581632);                  // 8 KB
    _Float16* w3l = (_Float16*)(ws + 589824);                  // 8 KB

    zero_loss_kernel<<<1, 1, 0, stream>>>(loss);
    e2_kernel<<<CB_N / 256, 256, 0, stream>>>(cb, e2);
    prep_cb<<<16, 256, 0, stream>>>(cb, cbh, cbl);
    prep_w<<<8, 256, 0, stream>>>(W1, W2, W3, w1h, w1l, w2h, w2l, w3h, w3l);
    fused_mlp_vq<<<NPTS / 64, 256, 0, stream>>>(
        obs, b1, b2, b3, w1h, w1l, w2h, w2l, w3h, w3l,
        cb, cbh, cbl, e2, msg, idxf, loss);
}

// Round 4
// 218.673 us; speedup vs baseline: 1.3872x; 1.0726x over previous
//
#include <hip/hip_runtime.h>

// VQSpeaker: obs[32,2048,128] -> 3-layer MLP -> x[65536,64] -> VQ argmin over
// codebook[2048,64] -> (msg = codebook[idx], idx, cmt_loss).
//
// Round 12: attack the VQ tile loop's latency (R11: VGPR=52 proved the
//           compiler elided the B-prefetch double-buffer -> per-tile L2
//           load-use stalls; screening's exec-mask branches ate ~200 cyc/iter).
//   (a) tile loop unrolled x2 with named A/B buffer generations -> the
//       prefetch is structurally live, allocator must keep ~32 B-VGPRs.
//   (b) branchless screening fast path (cndmask min-update + push predicate),
//       divergent atomicAdd path only under wave-uniform __any(push).
//       push iff max(d,bd_old) < min(d,bd_old)+MARG; pushed pair = loser.
//       Algebraically identical to R3's two-branch logic.
//   (c) zero_loss/e2/prep_cb/prep_w merged into one prep_all kernel
//       (3 fewer launch/drain gaps).
//           MLP phase, rescore, loss: R11-verbatim.
//
// d_out layout (float32): msg[4194304] | idx[65536] (as float) | loss[1]
// d_ws: e2[2048] | cbh bf16 256KB | cbl bf16 256KB | w1h/w1l 16KB ea |
//       w2h/w2l/w3h/w3l 8KB ea   (total ~584 KB)

#define NPTS    65536
#define IN_DIM  128
#define HID     64
#define OUT_DIM 64
#define CB_N    2048
#define MSG_ELEMS (NPTS * OUT_DIM)
#define LOSS_SCALE (1.0f / 4194304.0f)
#define MARG 0.5f          // R3-proven screening margin
#define CAND_CAP 512

typedef __attribute__((ext_vector_type(8))) short short8;
typedef _Float16 half8 __attribute__((ext_vector_type(8)));
typedef __attribute__((ext_vector_type(4))) float f32x4;

__device__ __forceinline__ unsigned short f2bf(float f) {
    unsigned u = __float_as_uint(f);
    u += 0x7FFF + ((u >> 16) & 1);          // RN-even to bf16
    return (unsigned short)(u >> 16);
}
__device__ __forceinline__ float bf2f(unsigned short h) {
    return __uint_as_float((unsigned)h << 16);
}

// ---- merged prep: blocks 0-15 prep_cb, 16-23 prep_w, 24-31 e2 (+loss=0) ----
__global__ __launch_bounds__(256) void prep_all(
    const float* __restrict__ cb,
    const float* __restrict__ W1, const float* __restrict__ W2,
    const float* __restrict__ W3,
    float* __restrict__ e2,
    unsigned short* __restrict__ cbh, unsigned short* __restrict__ cbl,
    _Float16* __restrict__ w1h, _Float16* __restrict__ w1l,
    _Float16* __restrict__ w2h, _Float16* __restrict__ w2l,
    _Float16* __restrict__ w3h, _Float16* __restrict__ w3l,
    float* __restrict__ loss)
{
    const int b = blockIdx.x, tid = threadIdx.x;
    if (b < 16) {
        // ---- prep_cb: codebook -> MFMA B-frag order, hi/lo bf16 ----
        const int id = b * 256 + tid;               // 0..4095: (code n, half h)
        const int n = id >> 1, h = id & 1;
        const int t = n >> 4, l15 = n & 15;
        const float* src = cb + (long)n * OUT_DIM + h * 32;
        #pragma unroll
        for (int quad = 0; quad < 4; ++quad) {
            short8 hi, lo;
            #pragma unroll
            for (int j = 0; j < 8; ++j) {
                const float f = src[quad * 8 + j];
                const unsigned short hb = f2bf(f);
                hi[j] = (short)hb;
                lo[j] = (short)f2bf(f - bf2f(hb));
            }
            const long dst = ((long)(t * 2 + h) * 64 + quad * 16 + l15) * 8;
            *(short8*)(cbh + dst) = hi;
            *(short8*)(cbl + dst) = lo;
        }
    } else if (b < 24) {
        // ---- prep_w: W1/W2/W3 -> MFMA B-frag order, fp16 hi/lo split ----
        const int id = (b - 16) * 256 + tid;        // 0..2047
        const int lane = id & 63;
        const int m = lane & 15, quad = lane >> 4;
        const float* W; _Float16 *dh, *dl; int frag;
        if (id < 1024)      { W = W1; dh = w1h; dl = w1l; frag = id >> 6; }
        else if (id < 1536) { W = W2; dh = w2h; dl = w2l; frag = (id - 1024) >> 6; }
        else                { W = W3; dh = w3h; dl = w3l; frag = (id - 1536) >> 6; }
        const int kc = frag >> 2, nt = frag & 3;
        half8 hi, lo;
        #pragma unroll
        for (int j = 0; j < 8; ++j) {
            const float v = W[(long)(kc * 32 + quad * 8 + j) * 64 + nt * 16 + m];
            hi[j] = (_Float16)v;
            lo[j] = (_Float16)(v - (float)hi[j]);
        }
        const long dst = (long)(frag * 64 + lane) * 8;
        *(half8*)(dh + dst) = hi;
        *(half8*)(dl + dst) = lo;
    } else {
        // ---- e2 + zero_loss ----
        if (b == 24 && tid == 0) *loss = 0.0f;
        const int c = (b - 24) * 256 + tid;
        const float4* row = (const float4*)(cb + (long)c * OUT_DIM);
        float s = 0.0f;
        #pragma unroll
        for (int mq = 0; mq < 16; ++mq) {
            const float4 v = row[mq];
            s += v.x * v.x + v.y * v.y + v.z * v.z + v.w * v.w;
        }
        e2[c] = s;
    }
}

#define MFMA16(A, B, C) __builtin_amdgcn_mfma_f32_16x16x32_f16(A, B, C, 0, 0, 0)
#define MFMABF(A, B, C) __builtin_amdgcn_mfma_f32_16x16x32_bf16(A, B, C, 0, 0, 0)

__device__ __forceinline__ void split16(const float* xs, half8& h, half8& l) {
    #pragma unroll
    for (int j = 0; j < 8; ++j) {
        h[j] = (_Float16)xs[j];
        l[j] = (_Float16)(xs[j] - (float)h[j]);
    }
}

// exact fp32 distance update (R2/R3 proven numerics); xr may be LDS.
__device__ __forceinline__ void exact_upd(
    const float* xr, const float* __restrict__ cb,
    const float* __restrict__ e2, int n, float& bd, int& bi)
{
    const float4* xp = (const float4*)xr;
    const float4* cp = (const float4*)(cb + (long)n * OUT_DIM);
    float a0 = 0.0f, a1 = 0.0f;
    #pragma unroll
    for (int m = 0; m < 16; ++m) {
        const float4 xv = xp[m], cv = cp[m];
        a0 = fmaf(xv.x, cv.x, a0); a1 = fmaf(xv.y, cv.y, a1);
        a0 = fmaf(xv.z, cv.z, a0); a1 = fmaf(xv.w, cv.w, a1);
    }
    const float ex = fmaf(-2.0f, a0 + a1, e2[n]);
    if (ex < bd || (ex == bd && n < bi)) { bd = ex; bi = n; }
}

// ---------------- FUSED: MLP (wave-local, x -> LDS) + VQ ----
// 64 pts/block, 4 waves; wave w owns points w*16..w*16+15 through the MLP and
// the VQ tile scan. x never touches global memory.
__global__ __launch_bounds__(256, 4) void fused_mlp_vq(
    const float* __restrict__ obs,
    const float* __restrict__ b1, const float* __restrict__ b2,
    const float* __restrict__ b3,
    const _Float16* __restrict__ w1h, const _Float16* __restrict__ w1l,
    const _Float16* __restrict__ w2h, const _Float16* __restrict__ w2l,
    const _Float16* __restrict__ w3h, const _Float16* __restrict__ w3l,
    const float* __restrict__ cb,
    const unsigned short* __restrict__ cbhp,
    const unsigned short* __restrict__ cblp,
    const float* __restrict__ e2,
    float* __restrict__ msg,        // out only: quantize
    float* __restrict__ idx_out,
    float* __restrict__ loss_out)
{
    __shared__ float hbuf[64 * 68];         // mlp scratch, then x[64][64] @68
    __shared__ float best_d_s[4][16][16];   // [wave][pt][col]
    __shared__ int   best_i_s[4][16][16];
    __shared__ int   cand_pc[CAND_CAP];     // (p_local<<16) | code
    __shared__ float cand_d[CAND_CAP];
    __shared__ int   cand_cnt;
    __shared__ int   idx_sh[64];
    __shared__ float wred[4];

    const int t = threadIdx.x, lane = t & 63, w = t >> 6;
    const int m = lane & 15, quad = lane >> 4;
    const long base = (long)blockIdx.x * 64;
    const int row0 = w * 16 + quad * 4;         // C-layout write rows (+r)
    const int arow_l = w * 16 + m;              // A-layout read row

    if (t == 0) cand_cnt = 0;

    // ================= MLP phase (R11-verbatim, wave-local) =================
    {
        float bb1[4], bb2[4], bb3[4];
        #pragma unroll
        for (int nt = 0; nt < 4; ++nt) {
            bb1[nt] = b1[nt * 16 + m];
            bb2[nt] = b2[nt * 16 + m];
            bb3[nt] = b3[nt * 16 + m];
        }

        const float* arow = obs + (base + w * 16 + m) * IN_DIM;
        half8 a1h[4], a1l[4];
        #pragma unroll
        for (int kc = 0; kc < 4; ++kc) {
            const float4 va = *(const float4*)(arow + kc * 32 + quad * 8);
            const float4 vb = *(const float4*)(arow + kc * 32 + quad * 8 + 4);
            const float xs[8] = {va.x, va.y, va.z, va.w, vb.x, vb.y, vb.z, vb.w};
            split16(xs, a1h[kc], a1l[kc]);
        }

        // layer 1
        #pragma unroll
        for (int nt = 0; nt < 4; ++nt) {
            f32x4 acc = {0.0f, 0.0f, 0.0f, 0.0f};
            #pragma unroll
            for (int kc = 0; kc < 4; ++kc) {
                const long fo = (long)((kc * 4 + nt) * 64 + lane) * 8;
                const half8 wh = *(const half8*)(w1h + fo);
                const half8 wl = *(const half8*)(w1l + fo);
                acc = MFMA16(a1h[kc], wh, acc);
                acc = MFMA16(a1l[kc], wh, acc);
                acc = MFMA16(a1h[kc], wl, acc);
            }
            #pragma unroll
            for (int r = 0; r < 4; ++r) {
                const float v = acc[r] + bb1[nt];
                hbuf[(row0 + r) * 68 + nt * 16 + m] = v > 0.0f ? v : 0.0f;
            }
        }

        // layer 2
        half8 a2h[2], a2l[2];
        #pragma unroll
        for (int kc = 0; kc < 2; ++kc) {
            const float4 va = *(const float4*)&hbuf[arow_l * 68 + kc * 32 + quad * 8];
            const float4 vb = *(const float4*)&hbuf[arow_l * 68 + kc * 32 + quad * 8 + 4];
            const float xs[8] = {va.x, va.y, va.z, va.w, vb.x, vb.y, vb.z, vb.w};
            split16(xs, a2h[kc], a2l[kc]);
        }
        #pragma unroll
        for (int nt = 0; nt < 4; ++nt) {
            f32x4 acc = {0.0f, 0.0f, 0.0f, 0.0f};
            #pragma unroll
            for (int kc = 0; kc < 2; ++kc) {
                const long fo = (long)((kc * 4 + nt) * 64 + lane) * 8;
                const half8 wh = *(const half8*)(w2h + fo);
                const half8 wl = *(const half8*)(w2l + fo);
                acc = MFMA16(a2h[kc], wh, acc);
                acc = MFMA16(a2l[kc], wh, acc);
                acc = MFMA16(a2h[kc], wl, acc);
            }
            #pragma unroll
            for (int r = 0; r < 4; ++r) {
                const float v = acc[r] + bb2[nt];
                hbuf[(row0 + r) * 68 + nt * 16 + m] = v > 0.0f ? v : 0.0f;
            }
        }

        // layer 3 -> x rows in hbuf
        half8 a3h[2], a3l[2];
        #pragma unroll
        for (int kc = 0; kc < 2; ++kc) {
            const float4 va = *(const float4*)&hbuf[arow_l * 68 + kc * 32 + quad * 8];
            const float4 vb = *(const float4*)&hbuf[arow_l * 68 + kc * 32 + quad * 8 + 4];
            const float xs[8] = {va.x, va.y, va.z, va.w, vb.x, vb.y, vb.z, vb.w};
            split16(xs, a3h[kc], a3l[kc]);
        }
        #pragma unroll
        for (int nt = 0; nt < 4; ++nt) {
            f32x4 acc = {0.0f, 0.0f, 0.0f, 0.0f};
            #pragma unroll
            for (int kc = 0; kc < 2; ++kc) {
                const long fo = (long)((kc * 4 + nt) * 64 + lane) * 8;
                const half8 wh = *(const half8*)(w3h + fo);
                const half8 wl = *(const half8*)(w3l + fo);
                acc = MFMA16(a3h[kc], wh, acc);
                acc = MFMA16(a3l[kc], wh, acc);
                acc = MFMA16(a3h[kc], wl, acc);
            }
            #pragma unroll
            for (int r = 0; r < 4; ++r)
                hbuf[(row0 + r) * 68 + nt * 16 + m] = acc[r] + bb3[nt];
        }
    }

    // ================= VQ phase =================
    // A-frags: x[point = w*16 + m][k = quad*8 + j] from LDS (wave-local rows).
    const float* xrow = &hbuf[(w * 16 + m) * 68];
    short8 a0h, a0l, a1h, a1l;
    {
        const float4 xa = *(const float4*)(xrow + quad * 8);
        const float4 xb = *(const float4*)(xrow + quad * 8 + 4);
        const float4 xc = *(const float4*)(xrow + 32 + quad * 8);
        const float4 xd = *(const float4*)(xrow + 32 + quad * 8 + 4);
        const float x0[8] = {xa.x, xa.y, xa.z, xa.w, xb.x, xb.y, xb.z, xb.w};
        const float x1[8] = {xc.x, xc.y, xc.z, xc.w, xd.x, xd.y, xd.z, xd.w};
        #pragma unroll
        for (int j = 0; j < 8; ++j) {
            unsigned short hb = f2bf(x0[j]);
            a0h[j] = (short)hb; a0l[j] = (short)f2bf(x0[j] - bf2f(hb));
            hb = f2bf(x1[j]);
            a1h[j] = (short)hb; a1l[j] = (short)f2bf(x1[j] - bf2f(hb));
        }
    }
    __syncthreads();   // cand_cnt + all hbuf x rows visible block-wide

    float bd[4] = {3.4e38f, 3.4e38f, 3.4e38f, 3.4e38f};
    int   bi[4] = {0, 0, 0, 0};

    const unsigned short* ph = cbhp + (long)lane * 8;
    const unsigned short* pl = cblp + (long)lane * 8;

    // one tile: e2 load + 6 MFMA + branchless screen, wave-uniform slow path
    auto do_tile = [&](const short8& th0, const short8& th1,
                       const short8& tl0, const short8& tl1, int tile) {
        const float e2v = e2[tile * 16 + m];
        f32x4 acc0 = {0.0f, 0.0f, 0.0f, 0.0f};
        f32x4 acc1 = {0.0f, 0.0f, 0.0f, 0.0f};
        acc0 = MFMABF(a0h, th0, acc0);
        acc1 = MFMABF(a1h, th1, acc1);
        acc0 = MFMABF(a0l, th0, acc0);
        acc1 = MFMABF(a1l, th1, acc1);
        acc0 = MFMABF(a0h, tl0, acc0);
        acc1 = MFMABF(a1h, tl1, acc1);

        const int code = tile * 16 + m;
        bool pushm[4]; float pv[4]; int pi[4];
        #pragma unroll
        for (int r = 0; r < 4; ++r) {
            const float d = fmaf(-2.0f, acc0[r] + acc1[r], e2v);
            const bool lt = d < bd[r];
            // push iff loser within MARG of winner (== R3's two push cases)
            pushm[r] = (d < bd[r] + MARG) & (bd[r] < d + MARG);
            pv[r] = lt ? bd[r] : d;          // loser's distance
            pi[r] = lt ? bi[r] : code;       // loser's code
            bd[r] = lt ? d : bd[r];
            bi[r] = lt ? code : bi[r];
        }
        if (__any((int)(pushm[0] | pushm[1] | pushm[2] | pushm[3]))) {
            #pragma unroll
            for (int r = 0; r < 4; ++r) {
                if (pushm[r]) {
                    const int slot = atomicAdd(&cand_cnt, 1);
                    if (slot < CAND_CAP) {
                        cand_pc[slot] = ((w * 16 + quad * 4 + r) << 16) | pi[r];
                        cand_d[slot]  = pv[r];
                    }
                }
            }
        }
    };

    // software pipeline, unrolled x2 with named buffer generations (no
    // rotation copies for the allocator to elide)
    short8 Ah0 = *(const short8*)(ph);
    short8 Ah1 = *(const short8*)(ph + 512);
    short8 Al0 = *(const short8*)(pl);
    short8 Al1 = *(const short8*)(pl + 512);

    for (int tile = 0; tile < 128; tile += 2) {
        const long o1 = (long)(tile + 1) * 1024;
        const short8 Bh0 = *(const short8*)(ph + o1);
        const short8 Bh1 = *(const short8*)(ph + o1 + 512);
        const short8 Bl0 = *(const short8*)(pl + o1);
        const short8 Bl1 = *(const short8*)(pl + o1 + 512);

        do_tile(Ah0, Ah1, Al0, Al1, tile);

        const long o2 = (long)((tile + 2 < 128) ? tile + 2 : 127) * 1024;
        Ah0 = *(const short8*)(ph + o2);
        Ah1 = *(const short8*)(ph + o2 + 512);
        Al0 = *(const short8*)(pl + o2);
        Al1 = *(const short8*)(pl + o2 + 512);

        do_tile(Bh0, Bh1, Bl0, Bl1, tile + 1);
    }

    // publish per-slot bests: point row = quad*4 + r, col = m
    #pragma unroll
    for (int r = 0; r < 4; ++r) {
        best_d_s[w][quad * 4 + r][m] = bd[r];
        best_i_s[w][quad * 4 + r][m] = bi[r];
    }
    __syncthreads();

    // exact-rescore stage: one thread per point (x read from LDS)
    if (t < 64) {
        const int p = t, ww = p >> 4, pi_ = p & 15;
        float dmin = 3.4e38f;
        #pragma unroll
        for (int c = 0; c < 16; ++c) dmin = fminf(dmin, best_d_s[ww][pi_][c]);
        const float thr = dmin + MARG;

        float fbd = 3.4e38f; int fbi = 1 << 30;
        const float* xr = &hbuf[p * 68];
        #pragma unroll
        for (int c = 0; c < 16; ++c)
            if (best_d_s[ww][pi_][c] <= thr)
                exact_upd(xr, cb, e2, best_i_s[ww][pi_][c], fbd, fbi);
        const int L = min(cand_cnt, CAND_CAP);
        for (int l = 0; l < L; ++l) {
            const int pc = cand_pc[l];
            if ((pc >> 16) == p && cand_d[l] <= thr)
                exact_upd(xr, cb, e2, pc & 0xFFFF, fbd, fbi);
        }
        idx_sh[p] = fbi;
        idx_out[base + p] = (float)fbi;
    }
    __syncthreads();

    // gather q, write msg (write-only), accumulate loss (x from LDS)
    float lsum = 0.0f;
    float4* mg = (float4*)(msg + base * OUT_DIM);
    #pragma unroll
    for (int mm = 0; mm < 4; ++mm) {
        const int v = t + 256 * mm;
        const int p = v >> 4, k4 = v & 15;
        const int code = idx_sh[p];
        const float4 q = ((const float4*)(cb + (long)code * OUT_DIM))[k4];
        const float4 xv = *(const float4*)&hbuf[p * 68 + k4 * 4];
        const float dx = q.x - xv.x, dy = q.y - xv.y;
        const float dz = q.z - xv.z, dw2 = q.w - xv.w;
        lsum += dx * dx + dy * dy + dz * dz + dw2 * dw2;
        mg[v] = q;
    }
    #pragma unroll
    for (int off = 32; off > 0; off >>= 1) lsum += __shfl_down(lsum, off, 64);
    if (lane == 0) wred[w] = lsum;
    __syncthreads();
    if (t == 0)
        atomicAdd(loss_out, (wred[0] + wred[1] + wred[2] + wred[3]) * LOSS_SCALE);
}

extern "C" void kernel_launch(void* const* d_in, const int* in_sizes, int n_in,
                              void* d_out, int out_size, void* d_ws, size_t ws_size,
                              hipStream_t stream) {
    const float* obs = (const float*)d_in[0];
    const float* W1  = (const float*)d_in[1];
    const float* b1  = (const float*)d_in[2];
    const float* W2  = (const float*)d_in[3];
    const float* b2  = (const float*)d_in[4];
    const float* W3  = (const float*)d_in[5];
    const float* b3  = (const float*)d_in[6];
    const float* cb  = (const float*)d_in[7];

    float* out  = (float*)d_out;
    float* msg  = out;
    float* idxf = out + MSG_ELEMS;
    float* loss = out + MSG_ELEMS + NPTS;

    char* ws = (char*)d_ws;
    float*          e2  = (float*)ws;                          // 8 KB
    unsigned short* cbh = (unsigned short*)(ws + 8192);        // 256 KB
    unsigned short* cbl = (unsigned short*)(ws + 270336);      // 256 KB
    _Float16* w1h = (_Float16*)(ws + 532480);                  // 16 KB
    _Float16* w1l = (_Float16*)(ws + 548864);                  // 16 KB
    _Float16* w2h = (_Float16*)(ws + 565248);                  // 8 KB
    _Float16* w2l = (_Float16*)(ws + 573440);                  // 8 KB
    _Float16* w3h = (_Float16*)(ws + 581632);                  // 8 KB
    _Float16* w3l = (_Float16*)(ws + 589824);                  // 8 KB

    prep_all<<<32, 256, 0, stream>>>(cb, W1, W2, W3, e2, cbh, cbl,
                                     w1h, w1l, w2h, w2l, w3h, w3l, loss);
    fused_mlp_vq<<<NPTS / 64, 256, 0, stream>>>(
        obs, b1, b2, b3, w1h, w1l, w2h, w2l, w3h, w3l,
        cb, cbh, cbl, e2, msg, idxf, loss);
}

// Round 5
// 198.298 us; speedup vs baseline: 1.5297x; 1.1027x over previous
//
#include <hip/hip_runtime.h>

// VQSpeaker: obs[32,2048,128] -> 3-layer MLP -> x[65536,64] -> VQ argmin over
// codebook[2048,64] -> (msg = codebook[idx], idx, cmt_loss).
//
// Round 13: shrink the VQ screen instead of re-scheduling it.
//   Screen now uses fp16 SINGLE-product (x_h * c_h, fp32 MFMA accum).
//   Error bound: 2*2^-11*|x||c| ~ 0.20 worst-case < MARG/2 = 0.25, so the
//   R3-proven candidate+exact-rescore machinery still captures the true
//   argmin (rescore is exact fp32, unchanged). Per tile: 6 MFMA -> 2 MFMA,
//   no dependent MFMA chains, codebook bytes halved (cbl gone), live set
//   ~55 VGPR (matches the allocator's 52-ish preference).
//   e2 staged to LDS once per block (broadcast ds_read per tile, no
//   dependent global load in the loop). LDS 38 KB -> still 4 blocks/CU.
//   MLP phase, screening logic, rescore, loss: R12-verbatim.
//
// d_out layout (float32): msg[4194304] | idx[65536] (as float) | loss[1]
// d_ws: e2[2048] | cbh fp16 256KB | (cbl slot unused) | w1h/w1l 16KB ea |
//       w2h/w2l/w3h/w3l 8KB ea

#define NPTS    65536
#define IN_DIM  128
#define HID     64
#define OUT_DIM 64
#define CB_N    2048
#define MSG_ELEMS (NPTS * OUT_DIM)
#define LOSS_SCALE (1.0f / 4194304.0f)
#define MARG 0.5f          // R3-proven screening margin
#define CAND_CAP 512

typedef __attribute__((ext_vector_type(8))) short short8;
typedef _Float16 half8 __attribute__((ext_vector_type(8)));
typedef __attribute__((ext_vector_type(4))) float f32x4;

__device__ __forceinline__ unsigned short f2bf(float f) {
    unsigned u = __float_as_uint(f);
    u += 0x7FFF + ((u >> 16) & 1);          // RN-even to bf16
    return (unsigned short)(u >> 16);
}
__device__ __forceinline__ float bf2f(unsigned short h) {
    return __uint_as_float((unsigned)h << 16);
}

// ---- merged prep: blocks 0-15 prep_cb, 16-23 prep_w, 24-31 e2 (+loss=0) ----
__global__ __launch_bounds__(256) void prep_all(
    const float* __restrict__ cb,
    const float* __restrict__ W1, const float* __restrict__ W2,
    const float* __restrict__ W3,
    float* __restrict__ e2,
    _Float16* __restrict__ cbh,
    _Float16* __restrict__ w1h, _Float16* __restrict__ w1l,
    _Float16* __restrict__ w2h, _Float16* __restrict__ w2l,
    _Float16* __restrict__ w3h, _Float16* __restrict__ w3l,
    float* __restrict__ loss)
{
    const int b = blockIdx.x, tid = threadIdx.x;
    if (b < 16) {
        // ---- prep_cb: codebook -> MFMA B-frag order, fp16 hi only ----
        const int id = b * 256 + tid;               // 0..4095: (code n, half h)
        const int n = id >> 1, h = id & 1;
        const int t = n >> 4, l15 = n & 15;
        const float* src = cb + (long)n * OUT_DIM + h * 32;
        #pragma unroll
        for (int quad = 0; quad < 4; ++quad) {
            half8 hi;
            #pragma unroll
            for (int j = 0; j < 8; ++j)
                hi[j] = (_Float16)src[quad * 8 + j];
            const long dst = ((long)(t * 2 + h) * 64 + quad * 16 + l15) * 8;
            *(half8*)(cbh + dst) = hi;
        }
    } else if (b < 24) {
        // ---- prep_w: W1/W2/W3 -> MFMA B-frag order, fp16 hi/lo split ----
        const int id = (b - 16) * 256 + tid;        // 0..2047
        const int lane = id & 63;
        const int m = lane & 15, quad = lane >> 4;
        const float* W; _Float16 *dh, *dl; int frag;
        if (id < 1024)      { W = W1; dh = w1h; dl = w1l; frag = id >> 6; }
        else if (id < 1536) { W = W2; dh = w2h; dl = w2l; frag = (id - 1024) >> 6; }
        else                { W = W3; dh = w3h; dl = w3l; frag = (id - 1536) >> 6; }
        const int kc = frag >> 2, nt = frag & 3;
        half8 hi, lo;
        #pragma unroll
        for (int j = 0; j < 8; ++j) {
            const float v = W[(long)(kc * 32 + quad * 8 + j) * 64 + nt * 16 + m];
            hi[j] = (_Float16)v;
            lo[j] = (_Float16)(v - (float)hi[j]);
        }
        const long dst = (long)(frag * 64 + lane) * 8;
        *(half8*)(dh + dst) = hi;
        *(half8*)(dl + dst) = lo;
    } else {
        // ---- e2 + zero_loss ----
        if (b == 24 && tid == 0) *loss = 0.0f;
        const int c = (b - 24) * 256 + tid;
        const float4* row = (const float4*)(cb + (long)c * OUT_DIM);
        float s = 0.0f;
        #pragma unroll
        for (int mq = 0; mq < 16; ++mq) {
            const float4 v = row[mq];
            s += v.x * v.x + v.y * v.y + v.z * v.z + v.w * v.w;
        }
        e2[c] = s;
    }
}

#define MFMA16(A, B, C) __builtin_amdgcn_mfma_f32_16x16x32_f16(A, B, C, 0, 0, 0)

__device__ __forceinline__ void split16(const float* xs, half8& h, half8& l) {
    #pragma unroll
    for (int j = 0; j < 8; ++j) {
        h[j] = (_Float16)xs[j];
        l[j] = (_Float16)(xs[j] - (float)h[j]);
    }
}

// exact fp32 distance update (R2/R3 proven numerics); xr may be LDS.
__device__ __forceinline__ void exact_upd(
    const float* xr, const float* __restrict__ cb,
    const float* __restrict__ e2, int n, float& bd, int& bi)
{
    const float4* xp = (const float4*)xr;
    const float4* cp = (const float4*)(cb + (long)n * OUT_DIM);
    float a0 = 0.0f, a1 = 0.0f;
    #pragma unroll
    for (int m = 0; m < 16; ++m) {
        const float4 xv = xp[m], cv = cp[m];
        a0 = fmaf(xv.x, cv.x, a0); a1 = fmaf(xv.y, cv.y, a1);
        a0 = fmaf(xv.z, cv.z, a0); a1 = fmaf(xv.w, cv.w, a1);
    }
    const float ex = fmaf(-2.0f, a0 + a1, e2[n]);
    if (ex < bd || (ex == bd && n < bi)) { bd = ex; bi = n; }
}

// ---------------- FUSED: MLP (wave-local, x -> LDS) + VQ ----
// 64 pts/block, 4 waves; wave w owns points w*16..w*16+15 through the MLP and
// the VQ tile scan. x never touches global memory.
__global__ __launch_bounds__(256, 4) void fused_mlp_vq(
    const float* __restrict__ obs,
    const float* __restrict__ b1, const float* __restrict__ b2,
    const float* __restrict__ b3,
    const _Float16* __restrict__ w1h, const _Float16* __restrict__ w1l,
    const _Float16* __restrict__ w2h, const _Float16* __restrict__ w2l,
    const _Float16* __restrict__ w3h, const _Float16* __restrict__ w3l,
    const float* __restrict__ cb,
    const _Float16* __restrict__ cbhp,
    const float* __restrict__ e2,
    float* __restrict__ msg,        // out only: quantize
    float* __restrict__ idx_out,
    float* __restrict__ loss_out)
{
    __shared__ float hbuf[64 * 68];         // mlp scratch, then x[64][64] @68
    __shared__ float e2s[CB_N];             // e2 staged once per block (8 KB)
    __shared__ float best_d_s[4][16][16];   // [wave][pt][col]
    __shared__ int   best_i_s[4][16][16];
    __shared__ int   cand_pc[CAND_CAP];     // (p_local<<16) | code
    __shared__ float cand_d[CAND_CAP];
    __shared__ int   cand_cnt;
    __shared__ int   idx_sh[64];
    __shared__ float wred[4];

    const int t = threadIdx.x, lane = t & 63, w = t >> 6;
    const int m = lane & 15, quad = lane >> 4;
    const long base = (long)blockIdx.x * 64;
    const int row0 = w * 16 + quad * 4;         // C-layout write rows (+r)
    const int arow_l = w * 16 + m;              // A-layout read row

    if (t == 0) cand_cnt = 0;

    // stage e2 -> LDS (2048 floats, 8 per thread, coalesced)
    {
        const float4 ea = ((const float4*)e2)[t * 2];
        const float4 eb = ((const float4*)e2)[t * 2 + 1];
        ((float4*)e2s)[t * 2]     = ea;
        ((float4*)e2s)[t * 2 + 1] = eb;
    }

    // ================= MLP phase (R12-verbatim, wave-local) =================
    {
        float bb1[4], bb2[4], bb3[4];
        #pragma unroll
        for (int nt = 0; nt < 4; ++nt) {
            bb1[nt] = b1[nt * 16 + m];
            bb2[nt] = b2[nt * 16 + m];
            bb3[nt] = b3[nt * 16 + m];
        }

        const float* arow = obs + (base + w * 16 + m) * IN_DIM;
        half8 a1h[4], a1l[4];
        #pragma unroll
        for (int kc = 0; kc < 4; ++kc) {
            const float4 va = *(const float4*)(arow + kc * 32 + quad * 8);
            const float4 vb = *(const float4*)(arow + kc * 32 + quad * 8 + 4);
            const float xs[8] = {va.x, va.y, va.z, va.w, vb.x, vb.y, vb.z, vb.w};
            split16(xs, a1h[kc], a1l[kc]);
        }

        // layer 1
        #pragma unroll
        for (int nt = 0; nt < 4; ++nt) {
            f32x4 acc = {0.0f, 0.0f, 0.0f, 0.0f};
            #pragma unroll
            for (int kc = 0; kc < 4; ++kc) {
                const long fo = (long)((kc * 4 + nt) * 64 + lane) * 8;
                const half8 wh = *(const half8*)(w1h + fo);
                const half8 wl = *(const half8*)(w1l + fo);
                acc = MFMA16(a1h[kc], wh, acc);
                acc = MFMA16(a1l[kc], wh, acc);
                acc = MFMA16(a1h[kc], wl, acc);
            }
            #pragma unroll
            for (int r = 0; r < 4; ++r) {
                const float v = acc[r] + bb1[nt];
                hbuf[(row0 + r) * 68 + nt * 16 + m] = v > 0.0f ? v : 0.0f;
            }
        }

        // layer 2
        half8 a2h[2], a2l[2];
        #pragma unroll
        for (int kc = 0; kc < 2; ++kc) {
            const float4 va = *(const float4*)&hbuf[arow_l * 68 + kc * 32 + quad * 8];
            const float4 vb = *(const float4*)&hbuf[arow_l * 68 + kc * 32 + quad * 8 + 4];
            const float xs[8] = {va.x, va.y, va.z, va.w, vb.x, vb.y, vb.z, vb.w};
            split16(xs, a2h[kc], a2l[kc]);
        }
        #pragma unroll
        for (int nt = 0; nt < 4; ++nt) {
            f32x4 acc = {0.0f, 0.0f, 0.0f, 0.0f};
            #pragma unroll
            for (int kc = 0; kc < 2; ++kc) {
                const long fo = (long)((kc * 4 + nt) * 64 + lane) * 8;
                const half8 wh = *(const half8*)(w2h + fo);
                const half8 wl = *(const half8*)(w2l + fo);
                acc = MFMA16(a2h[kc], wh, acc);
                acc = MFMA16(a2l[kc], wh, acc);
                acc = MFMA16(a2h[kc], wl, acc);
            }
            #pragma unroll
            for (int r = 0; r < 4; ++r) {
                const float v = acc[r] + bb2[nt];
                hbuf[(row0 + r) * 68 + nt * 16 + m] = v > 0.0f ? v : 0.0f;
            }
        }

        // layer 3 -> x rows in hbuf
        half8 a3h[2], a3l[2];
        #pragma unroll
        for (int kc = 0; kc < 2; ++kc) {
            const float4 va = *(const float4*)&hbuf[arow_l * 68 + kc * 32 + quad * 8];
            const float4 vb = *(const float4*)&hbuf[arow_l * 68 + kc * 32 + quad * 8 + 4];
            const float xs[8] = {va.x, va.y, va.z, va.w, vb.x, vb.y, vb.z, vb.w};
            split16(xs, a3h[kc], a3l[kc]);
        }
        #pragma unroll
        for (int nt = 0; nt < 4; ++nt) {
            f32x4 acc = {0.0f, 0.0f, 0.0f, 0.0f};
            #pragma unroll
            for (int kc = 0; kc < 2; ++kc) {
                const long fo = (long)((kc * 4 + nt) * 64 + lane) * 8;
                const half8 wh = *(const half8*)(w3h + fo);
                const half8 wl = *(const half8*)(w3l + fo);
                acc = MFMA16(a3h[kc], wh, acc);
                acc = MFMA16(a3l[kc], wh, acc);
                acc = MFMA16(a3h[kc], wl, acc);
            }
            #pragma unroll
            for (int r = 0; r < 4; ++r)
                hbuf[(row0 + r) * 68 + nt * 16 + m] = acc[r] + bb3[nt];
        }
    }

    // ================= VQ phase: fp16 single-product screen =================
    // A-frags: x[point = w*16 + m][k = quad*8 + j] from LDS (wave-local rows).
    const float* xrow = &hbuf[(w * 16 + m) * 68];
    half8 a0h, a1h;
    {
        const float4 xa = *(const float4*)(xrow + quad * 8);
        const float4 xb = *(const float4*)(xrow + quad * 8 + 4);
        const float4 xc = *(const float4*)(xrow + 32 + quad * 8);
        const float4 xd = *(const float4*)(xrow + 32 + quad * 8 + 4);
        const float x0[8] = {xa.x, xa.y, xa.z, xa.w, xb.x, xb.y, xb.z, xb.w};
        const float x1[8] = {xc.x, xc.y, xc.z, xc.w, xd.x, xd.y, xd.z, xd.w};
        #pragma unroll
        for (int j = 0; j < 8; ++j) {
            a0h[j] = (_Float16)x0[j];
            a1h[j] = (_Float16)x1[j];
        }
    }
    __syncthreads();   // cand_cnt + e2s + all hbuf x rows visible block-wide

    float bd[4] = {3.4e38f, 3.4e38f, 3.4e38f, 3.4e38f};
    int   bi[4] = {0, 0, 0, 0};

    const _Float16* ph = cbhp + (long)lane * 8;

    // one tile: e2 ds_read + 2 independent MFMA + branchless screen,
    // wave-uniform slow path for candidate pushes
    auto do_tile = [&](const half8& th0, const half8& th1, int tile) {
        const float e2v = e2s[tile * 16 + m];
        f32x4 acc0 = {0.0f, 0.0f, 0.0f, 0.0f};
        f32x4 acc1 = {0.0f, 0.0f, 0.0f, 0.0f};
        acc0 = MFMA16(a0h, th0, acc0);
        acc1 = MFMA16(a1h, th1, acc1);

        const int code = tile * 16 + m;
        bool pushm[4]; float pv[4]; int pi[4];
        #pragma unroll
        for (int r = 0; r < 4; ++r) {
            const float d = fmaf(-2.0f, acc0[r] + acc1[r], e2v);
            const bool lt = d < bd[r];
            // push iff loser within MARG of winner (== R3's two push cases)
            pushm[r] = (d < bd[r] + MARG) & (bd[r] < d + MARG);
            pv[r] = lt ? bd[r] : d;          // loser's distance
            pi[r] = lt ? bi[r] : code;       // loser's code
            bd[r] = lt ? d : bd[r];
            bi[r] = lt ? code : bi[r];
        }
        if (__any((int)(pushm[0] | pushm[1] | pushm[2] | pushm[3]))) {
            #pragma unroll
            for (int r = 0; r < 4; ++r) {
                if (pushm[r]) {
                    const int slot = atomicAdd(&cand_cnt, 1);
                    if (slot < CAND_CAP) {
                        cand_pc[slot] = ((w * 16 + quad * 4 + r) << 16) | pi[r];
                        cand_d[slot]  = pv[r];
                    }
                }
            }
        }
    };

    // software pipeline, unrolled x2 with named buffer generations
    half8 Ah0 = *(const half8*)(ph);
    half8 Ah1 = *(const half8*)(ph + 512);

    for (int tile = 0; tile < 128; tile += 2) {
        const long o1 = (long)(tile + 1) * 1024;
        const half8 Bh0 = *(const half8*)(ph + o1);
        const half8 Bh1 = *(const half8*)(ph + o1 + 512);

        do_tile(Ah0, Ah1, tile);

        const long o2 = (long)((tile + 2 < 128) ? tile + 2 : 127) * 1024;
        Ah0 = *(const half8*)(ph + o2);
        Ah1 = *(const half8*)(ph + o2 + 512);

        do_tile(Bh0, Bh1, tile + 1);
    }

    // publish per-slot bests: point row = quad*4 + r, col = m
    #pragma unroll
    for (int r = 0; r < 4; ++r) {
        best_d_s[w][quad * 4 + r][m] = bd[r];
        best_i_s[w][quad * 4 + r][m] = bi[r];
    }
    __syncthreads();

    // exact-rescore stage: one thread per point (x read from LDS)
    if (t < 64) {
        const int p = t, ww = p >> 4, pi_ = p & 15;
        float dmin = 3.4e38f;
        #pragma unroll
        for (int c = 0; c < 16; ++c) dmin = fminf(dmin, best_d_s[ww][pi_][c]);
        const float thr = dmin + MARG;

        float fbd = 3.4e38f; int fbi = 1 << 30;
        const float* xr = &hbuf[p * 68];
        #pragma unroll
        for (int c = 0; c < 16; ++c)
            if (best_d_s[ww][pi_][c] <= thr)
                exact_upd(xr, cb, e2, best_i_s[ww][pi_][c], fbd, fbi);
        const int L = min(cand_cnt, CAND_CAP);
        for (int l = 0; l < L; ++l) {
            const int pc = cand_pc[l];
            if ((pc >> 16) == p && cand_d[l] <= thr)
                exact_upd(xr, cb, e2, pc & 0xFFFF, fbd, fbi);
        }
        idx_sh[p] = fbi;
        idx_out[base + p] = (float)fbi;
    }
    __syncthreads();

    // gather q, write msg (write-only), accumulate loss (x from LDS)
    float lsum = 0.0f;
    float4* mg = (float4*)(msg + base * OUT_DIM);
    #pragma unroll
    for (int mm = 0; mm < 4; ++mm) {
        const int v = t + 256 * mm;
        const int p = v >> 4, k4 = v & 15;
        const int code = idx_sh[p];
        const float4 q = ((const float4*)(cb + (long)code * OUT_DIM))[k4];
        const float4 xv = *(const float4*)&hbuf[p * 68 + k4 * 4];
        const float dx = q.x - xv.x, dy = q.y - xv.y;
        const float dz = q.z - xv.z, dw2 = q.w - xv.w;
        lsum += dx * dx + dy * dy + dz * dz + dw2 * dw2;
        mg[v] = q;
    }
    #pragma unroll
    for (int off = 32; off > 0; off >>= 1) lsum += __shfl_down(lsum, off, 64);
    if (lane == 0) wred[w] = lsum;
    __syncthreads();
    if (t == 0)
        atomicAdd(loss_out, (wred[0] + wred[1] + wred[2] + wred[3]) * LOSS_SCALE);
}

extern "C" void kernel_launch(void* const* d_in, const int* in_sizes, int n_in,
                              void* d_out, int out_size, void* d_ws, size_t ws_size,
                              hipStream_t stream) {
    const float* obs = (const float*)d_in[0];
    const float* W1  = (const float*)d_in[1];
    const float* b1  = (const float*)d_in[2];
    const float* W2  = (const float*)d_in[3];
    const float* b2  = (const float*)d_in[4];
    const float* W3  = (const float*)d_in[5];
    const float* b3  = (const float*)d_in[6];
    const float* cb  = (const float*)d_in[7];

    float* out  = (float*)d_out;
    float* msg  = out;
    float* idxf = out + MSG_ELEMS;
    float* loss = out + MSG_ELEMS + NPTS;

    char* ws = (char*)d_ws;
    float*     e2  = (float*)ws;                          // 8 KB
    _Float16*  cbh = (_Float16*)(ws + 8192);              // 256 KB (fp16 hi)
    _Float16* w1h = (_Float16*)(ws + 532480);             // 16 KB
    _Float16* w1l = (_Float16*)(ws + 548864);             // 16 KB
    _Float16* w2h = (_Float16*)(ws + 565248);             // 8 KB
    _Float16* w2l = (_Float16*)(ws + 573440);             // 8 KB
    _Float16* w3h = (_Float16*)(ws + 581632);             // 8 KB
    _Float16* w3l = (_Float16*)(ws + 589824);             // 8 KB

    prep_all<<<32, 256, 0, stream>>>(cb, W1, W2, W3, e2, cbh,
                                     w1h, w1l, w2h, w2l, w3h, w3l, loss);
    fused_mlp_vq<<<NPTS / 64, 256, 0, stream>>>(
        obs, b1, b2, b3, w1h, w1l, w2h, w2l, w3h, w3l,
        cb, cbh, e2, msg, idxf, loss);
}